// Round 15
// baseline (105.455 us; speedup 1.0000x reference)
//
#include <hip/hip_runtime.h>
#include <math.h>

typedef __attribute__((ext_vector_type(8))) short short8;
typedef __attribute__((ext_vector_type(4))) float f32x4;

#define NB   8
#define CIN  128
#define CC   256
#define GG   8
#define CGR  32
#define HH   36
#define WW   36
#define HWP  1296
#define DHH  34
#define DD   1156

#define PPW  38
#define PPN  1444

#define KB_D 1216                 // kb d-slots padded to 19*64 (zeroed pad)
#define VBT_STRIDE 1216           // vbt row padded to 19*64 (zeroed pad)
#define VBT_NG     (32 * VBT_STRIDE)

#define AW   8                    // attention waves per block
#define KS   40
#define VS   72
#define WS2  72

#define NPROJB 1152                       // proj blocks: 4 oc-chunks x 36 rows x 8 n
#define NPACK  (3 * 8 * 9 * 32 * 32)      // 221184
#define NPACKG (8 * 3 * 10 * 32 * 32)     // 245760
#define ZPERNG (2432 + 2304 + 1920 + 1920)// 8576 pad shorts per (n,g)
#define NZERO  (64 * ZPERNG)              // 548864
#define NINIT  (NPACK + NPACKG + NZERO)   // 1015808
#define NINITB ((NINIT + 255) / 256)      // 3968

__device__ inline short f2bf(float f) {
    union { float f; unsigned u; } v; v.f = f;
    unsigned r = v.u + 0x7fffu + ((v.u >> 16) & 1u);
    return (short)(r >> 16);
}

__device__ inline float sigm(float z) { return 1.f / (1.f + __expf(-z)); }
__device__ inline float tanh_fast(float z) { return 2.f / (1.f + __expf(-2.f * z)) - 1.f; }

// ---------------- fused init + proj ----------------
// blocks [0, NINITB): weight packs + pad zeroing (short blocks, drain first)
// blocks [NINITB, ..): 1x1 projection. 1152 small blocks (64 oc x 1 row x n),
// 18 KB LDS -> 8 blocks/CU residency; latency hidden by TLP, not ILP.
__global__ __launch_bounds__(256) void k_initP(const float* __restrict__ x_in,
                                               const float* __restrict__ W_xi,
                                               const float* __restrict__ Wq,
                                               const float* __restrict__ Wk,
                                               const float* __restrict__ Wv,
                                               const float* __restrict__ tau,
                                               const float* __restrict__ Wi_x, const float* __restrict__ Wi_a,
                                               const float* __restrict__ Wg_x, const float* __restrict__ Wg_a,
                                               const float* __restrict__ Wo_x, const float* __restrict__ Wo_a,
                                               short* __restrict__ wpk,
                                               short* __restrict__ wgpk,
                                               short* __restrict__ kb,
                                               short* __restrict__ vbt,
                                               short* __restrict__ xpb) {
    __shared__ float xs[CIN * 36];
    int bid = blockIdx.x;
    if (bid >= NINITB) {
        // ---- proj: one row (36 px), 64 oc, 9 px per thread ----
        int pb = bid - NINITB;
        int chunk = pb & 3, row = (pb >> 2) % 36, n = pb / 144;
        const float* xb = x_in + (size_t)n * CIN * HWP + row * 36;
        for (int idx = threadIdx.x; idx < CIN * 36; idx += 256) {
            int ci = idx / 36, c = idx % 36;
            xs[idx] = xb[ci * HWP + c];
        }
        __syncthreads();
        int oc = chunk * 64 + (threadIdx.x >> 2);
        int j = threadIdx.x & 3;                 // 9-px quarter of the row
        const float* w = W_xi + oc * CIN;
        const float* xsj = xs + j * 9;
        float acc[9];
        #pragma unroll
        for (int t = 0; t < 9; t++) acc[t] = 0.f;
        for (int ci4 = 0; ci4 < CIN / 4; ci4++) {
            float4 wv4 = *(const float4*)(w + ci4 * 4);
            const float* xr0 = xsj + (ci4 * 4 + 0) * 36;
            const float* xr1 = xsj + (ci4 * 4 + 1) * 36;
            const float* xr2 = xsj + (ci4 * 4 + 2) * 36;
            const float* xr3 = xsj + (ci4 * 4 + 3) * 36;
            #pragma unroll
            for (int t = 0; t < 9; t++)
                acc[t] += wv4.x * xr0[t] + wv4.y * xr1[t] + wv4.z * xr2[t] + wv4.w * xr3[t];
        }
        int g = oc >> 5, c = oc & 31;
        short* xpw = xpb + ((size_t)(n * GG + g) * PPN + (size_t)(row + 1) * PPW + j * 9 + 1) * 32 + c;
        #pragma unroll
        for (int t = 0; t < 9; t++) xpw[t * 32] = f2bf(acc[t]);
        return;
    }

    int idx = bid * 256 + threadIdx.x;
    if (idx < NPACK) {
        int cpos = idx & 31;
        int oc   = (idx >> 5) & 31;
        int tap  = (idx >> 10) % 9;
        int cg   = idx / 9216;
        int conv = cg >> 3, g = cg & 7;
        int ci = cpos ^ ((oc & 3) << 3);
        const float* W = (conv == 0) ? Wq : (conv == 1) ? Wk : Wv;
        float v = W[(size_t)(g * 32 + oc) * 576 + ci * 9 + tap];
        if (conv == 0) v *= tau[g] * 1.4426950408889634f;
        wpk[idx] = f2bf(v);
        return;
    }
    idx -= NPACK;
    if (idx < NPACKG) {
        int cpos = idx & 31;
        int oc   = (idx >> 5) & 31;
        int tap  = (idx >> 10) % 10;
        int gg_  = idx / 10240;
        int g    = gg_ / 3, gate = gg_ % 3;
        int ci = cpos ^ ((oc & 3) << 3);
        const float* Wx = (gate == 0) ? Wi_x : (gate == 1) ? Wg_x : Wo_x;
        const float* Wa = (gate == 0) ? Wi_a : (gate == 1) ? Wg_a : Wo_a;
        float v = (tap < 9) ? Wx[(size_t)(g * 32 + oc) * 576 + ci * 9 + tap]
                            : Wa[(g * 32 + oc) * 32 + ci];
        wgpk[idx] = f2bf(v);
        return;
    }
    idx -= NPACKG;
    if (idx >= NZERO) return;
    int ng = idx / ZPERNG;
    int r  = idx % ZPERNG;
    if (r < 2432) {
        int row = (r < 1216) ? 0 : 37;
        int off = (r < 1216) ? r : r - 1216;
        xpb[(size_t)ng * PPN * 32 + (size_t)row * 1216 + off] = 0;
    } else if (r < 4736) {
        int r2 = r - 2432;
        int row = 1 + r2 / 64;
        int rem = r2 % 64;
        int col = (rem < 32) ? 0 : 37;
        int ch = rem & 31;
        xpb[(size_t)ng * PPN * 32 + (size_t)(row * PPW + col) * 32 + ch] = 0;
    } else if (r < 6656) {
        int r3 = r - 4736;
        kb[(size_t)ng * KB_D * 32 + (size_t)DD * 32 + r3] = 0;
    } else {
        int r4 = r - 6656;
        int c = r4 / 60, d = r4 % 60;
        vbt[(size_t)ng * VBT_NG + (size_t)c * VBT_STRIDE + DD + d] = 0;
    }
}

// ---------------- MFMA grouped 3x3 conv for q/k/v (verbatim round-12, proven) ----------------
__global__ __launch_bounds__(256) void k_qkvM(const short* __restrict__ xpb,
                                              const short* __restrict__ wpk,
                                              short* __restrict__ qb,
                                              short* __restrict__ kb,
                                              short* __restrict__ vbt) {
    __shared__ short w_lds[9 * 32 * 32];
    int ng = blockIdx.x, chunk = blockIdx.y, conv = blockIdx.z;
    int n = ng >> 3, g = ng & 7;

    const short* wsrc = wpk + (size_t)(conv * 8 + g) * 9216;
    for (int idx = threadIdx.x; idx < 1152; idx += 256)
        *(uint4*)(&w_lds[idx * 8]) = *(const uint4*)(wsrc + idx * 8);
    __syncthreads();

    int tid = threadIdx.x;
    int wv = tid >> 6, ln = tid & 63, lo = ln & 15, hi = ln >> 4;
    const short* xg = xpb + (size_t)(n * GG + g) * PPN * 32;
    int swz = (hi * 8) ^ ((lo & 3) << 3);

    f32x4 acc[3][2];
    #pragma unroll
    for (int tt = 0; tt < 3; tt++)
        #pragma unroll
        for (int ot = 0; ot < 2; ot++) acc[tt][ot] = (f32x4){0.f, 0.f, 0.f, 0.f};

    int tbase = chunk * 12 + wv * 3;
    #pragma unroll
    for (int tt = 0; tt < 3; tt++) {
        int tile = tbase + tt;
        if (tile < 81) {
            int p = tile * 16 + lo;
            int y = p / 36, xx = p - y * 36;
            const short* ab = xg + ((size_t)((y + 1) * PPW + xx + 1) * 32 + hi * 8);
            #pragma unroll
            for (int tap = 0; tap < 9; tap++) {
                int toff = (tap / 3 - 1) * PPW + (tap % 3 - 1);
                short8 af = *(const short8*)(ab + toff * 32);
                short8 b0 = *(const short8*)(&w_lds[tap * 1024 + lo * 32 + swz]);
                short8 b1 = *(const short8*)(&w_lds[tap * 1024 + (16 + lo) * 32 + swz]);
                acc[tt][0] = __builtin_amdgcn_mfma_f32_16x16x32_bf16(af, b0, acc[tt][0], 0, 0, 0);
                acc[tt][1] = __builtin_amdgcn_mfma_f32_16x16x32_bf16(af, b1, acc[tt][1], 0, 0, 0);
            }
        }
    }

    size_t bofs = (size_t)n * GG + g;
    #pragma unroll
    for (int tt = 0; tt < 3; tt++) {
        int tile = tbase + tt;
        if (tile < 81) {
            #pragma unroll
            for (int r = 0; r < 4; r++) {
                int p = tile * 16 + hi * 4 + r;
                int y = p / 36, xx = p - y * 36;
                #pragma unroll
                for (int ot = 0; ot < 2; ot++) {
                    short val = f2bf(acc[tt][ot][r]);
                    int oc = ot * 16 + lo;
                    if (conv == 0) {
                        qb[bofs * ((size_t)HWP * 32) + (size_t)p * 32 + oc] = val;
                    } else if ((unsigned)(y - 1) < DHH && (unsigned)(xx - 1) < DHH) {
                        int d = (y - 1) * DHH + (xx - 1);
                        if (conv == 1) kb[bofs * ((size_t)KB_D * 32) + (size_t)d * 32 + oc] = val;
                        else           vbt[bofs * (size_t)VBT_NG + (size_t)oc * VBT_STRIDE + d] = val;
                    }
                }
            }
        }
    }
}

// ---------------- MFMA attention: 8 waves/block, double-buffered LDS staging ----------------
// (verbatim round-9 kernel — known good)
__global__ __launch_bounds__(512) void k_attn(const short* __restrict__ qb,
                                              const short* __restrict__ kb,
                                              const short* __restrict__ vbt,
                                              short* __restrict__ a_b) {
    __shared__ short k_s[2][64 * KS];
    __shared__ short v_s[2][32 * VS];
    __shared__ short w_s[AW][16 * WS2];

    int ng = blockIdx.x, qc = blockIdx.y;
    int tid = threadIdx.x;
    int wv = tid >> 6, ln = tid & 63;
    int lo = ln & 15, hi = ln >> 4;
    const short* qg = qb + (size_t)ng * HWP * 32;
    const short* kg = kb + (size_t)ng * KB_D * 32;
    const short* vg = vbt + (size_t)ng * VBT_NG;
    short* ag = a_b + (size_t)ng * HWP * 32;

    int tile = qc * AW + wv;
    bool tv = (tile < 81);
    short8 qf = (short8){0,0,0,0,0,0,0,0};
    if (tv) qf = *(const short8*)(qg + (size_t)(tile * 16 + lo) * 32 + hi * 8);

    int kd = tid >> 2, kco = (tid & 3) << 3;
    int vc = (tid >> 3) & 31, vdo = (tid & 7) << 3;
    bool isK = (tid < 256);

    f32x4 oacc[2];
    oacc[0] = (f32x4){0.f, 0.f, 0.f, 0.f};
    oacc[1] = (f32x4){0.f, 0.f, 0.f, 0.f};
    float rs = 0.f;
    const f32x4 fz = {0.f, 0.f, 0.f, 0.f};

    {
        uint4 s0;
        if (isK) s0 = *(const uint4*)(kg + (size_t)kd * 32 + kco);
        else     s0 = *(const uint4*)(vg + (size_t)vc * VBT_STRIDE + vdo);
        if (isK) *(uint4*)(&k_s[0][kd * KS + kco]) = s0;
        else     *(uint4*)(&v_s[0][vc * VS + vdo]) = s0;
    }
    __syncthreads();

    for (int dt = 0; dt < 19; dt++) {
        int cur = dt & 1, nxt = cur ^ 1;
        uint4 nreg;
        if (dt < 18) {
            int d1 = (dt + 1) << 6;
            if (isK) nreg = *(const uint4*)(kg + (size_t)(d1 + kd) * 32 + kco);
            else     nreg = *(const uint4*)(vg + (size_t)vc * VBT_STRIDE + d1 + vdo);
        }

        if (tv) {
            #pragma unroll
            for (int sub = 0; sub < 4; sub++) {
                short8 kf = *(const short8*)(&k_s[cur][(sub * 16 + lo) * KS + hi * 8]);
                f32x4 s2 = __builtin_amdgcn_mfma_f32_16x16x32_bf16(kf, qf, fz, 0, 0, 0);
                float w0, w1, w2, w3;
                asm("v_exp_f32 %0, %1" : "=v"(w0) : "v"(s2[0]));
                asm("v_exp_f32 %0, %1" : "=v"(w1) : "v"(s2[1]));
                asm("v_exp_f32 %0, %1" : "=v"(w2) : "v"(s2[2]));
                asm("v_exp_f32 %0, %1" : "=v"(w3) : "v"(s2[3]));
                rs += (w0 + w1) + (w2 + w3);
                unsigned p01, p23;
                asm("v_cvt_pk_bf16_f32 %0, %1, %2" : "=v"(p01) : "v"(w0), "v"(w1));
                asm("v_cvt_pk_bf16_f32 %0, %1, %2" : "=v"(p23) : "v"(w2), "v"(w3));
                uint2 pk; pk.x = p01; pk.y = p23;
                *(uint2*)(&w_s[wv][lo * WS2 + sub * 16 + hi * 4]) = pk;
            }
            #pragma unroll
            for (int h = 0; h < 2; h++) {
                short8 af = *(const short8*)(&w_s[wv][lo * WS2 + h * 32 + hi * 8]);
                #pragma unroll
                for (int cs = 0; cs < 2; cs++) {
                    short8 vf = *(const short8*)(&v_s[cur][(cs * 16 + lo) * VS + h * 32 + hi * 8]);
                    oacc[cs] = __builtin_amdgcn_mfma_f32_16x16x32_bf16(af, vf, oacc[cs], 0, 0, 0);
                }
            }
        }

        if (dt < 18) {
            if (isK) *(uint4*)(&k_s[nxt][kd * KS + kco]) = nreg;
            else     *(uint4*)(&v_s[nxt][vc * VS + vdo]) = nreg;
        }
        __syncthreads();
    }

    float s = rs;
    s += __shfl_xor(s, 16);
    s += __shfl_xor(s, 32);
    float inv = 1.f / (s - 60.f);

    if (tv) {
        #pragma unroll
        for (int r = 0; r < 4; r++) {
            float iv = __shfl(inv, hi * 4 + r);
            int row = tile * 16 + hi * 4 + r;
            #pragma unroll
            for (int cs = 0; cs < 2; cs++)
                ag[(size_t)row * 32 + cs * 16 + lo] = f2bf(oacc[cs][r] * iv);
        }
    }
}

// ---------------- MFMA gates: i/g/o (f dead) + fused LSTM epilogue ----------------
__global__ __launch_bounds__(256) void k_gatesM(const short* __restrict__ xpb,
                                                const short* __restrict__ a_b,
                                                const short* __restrict__ wgpk,
                                                const float* __restrict__ b_i, const float* __restrict__ g_i,
                                                const float* __restrict__ b_g, const float* __restrict__ g_g,
                                                const float* __restrict__ b_o, const float* __restrict__ g_o,
                                                float* __restrict__ out) {
    __shared__ short w_lds[3 * 10 * 32 * 32];
    int ng = blockIdx.x, chunk = blockIdx.y;
    int n = ng >> 3, g = ng & 7;

    const short* wsrc = wgpk + (size_t)g * 30720;
    for (int idx = threadIdx.x; idx < 3840; idx += 256)
        *(uint4*)(&w_lds[idx * 8]) = *(const uint4*)(wsrc + idx * 8);
    __syncthreads();

    int tid = threadIdx.x;
    int wv = tid >> 6, ln = tid & 63, lo = ln & 15, hi = ln >> 4;
    const short* xg = xpb + (size_t)(n * GG + g) * PPN * 32;
    const short* ab_a = a_b + (size_t)(n * GG + g) * HWP * 32;
    int swz = (hi * 8) ^ ((lo & 3) << 3);

    f32x4 acc[3][3][2];
    #pragma unroll
    for (int gt = 0; gt < 3; gt++)
        #pragma unroll
        for (int tt = 0; tt < 3; tt++)
            #pragma unroll
            for (int ot = 0; ot < 2; ot++) acc[gt][tt][ot] = (f32x4){0.f, 0.f, 0.f, 0.f};

    int tbase = chunk * 12 + wv * 3;
    bool tv[3];
    int pbase[3];
    #pragma unroll
    for (int tt = 0; tt < 3; tt++) {
        int tile = tbase + tt;
        tv[tt] = (tile < 81);
        int p = tile * 16 + lo;
        int y = p / 36, xx = p - y * 36;
        pbase[tt] = ((y + 1) * PPW + xx + 1) * 32 + hi * 8;
    }

    #pragma unroll
    for (int tap = 0; tap < 9; tap++) {
        int toff = (tap / 3 - 1) * PPW + (tap % 3 - 1);
        short8 af[3];
        #pragma unroll
        for (int tt = 0; tt < 3; tt++) {
            af[tt] = (short8){0,0,0,0,0,0,0,0};
            if (tv[tt]) af[tt] = *(const short8*)(xg + pbase[tt] + toff * 32);
        }
        #pragma unroll
        for (int gt = 0; gt < 3; gt++) {
            const short* wl = &w_lds[(gt * 10 + tap) * 1024];
            short8 b0 = *(const short8*)(&wl[lo * 32 + swz]);
            short8 b1 = *(const short8*)(&wl[(16 + lo) * 32 + swz]);
            #pragma unroll
            for (int tt = 0; tt < 3; tt++) {
                acc[gt][tt][0] = __builtin_amdgcn_mfma_f32_16x16x32_bf16(af[tt], b0, acc[gt][tt][0], 0, 0, 0);
                acc[gt][tt][1] = __builtin_amdgcn_mfma_f32_16x16x32_bf16(af[tt], b1, acc[gt][tt][1], 0, 0, 0);
            }
        }
    }
    {
        short8 af[3];
        #pragma unroll
        for (int tt = 0; tt < 3; tt++) {
            af[tt] = (short8){0,0,0,0,0,0,0,0};
            if (tv[tt]) af[tt] = *(const short8*)(ab_a + (size_t)((tbase + tt) * 16 + lo) * 32 + hi * 8);
        }
        #pragma unroll
        for (int gt = 0; gt < 3; gt++) {
            const short* wl = &w_lds[(gt * 10 + 9) * 1024];
            short8 b0 = *(const short8*)(&wl[lo * 32 + swz]);
            short8 b1 = *(const short8*)(&wl[(16 + lo) * 32 + swz]);
            #pragma unroll
            for (int tt = 0; tt < 3; tt++) {
                acc[gt][tt][0] = __builtin_amdgcn_mfma_f32_16x16x32_bf16(af[tt], b0, acc[gt][tt][0], 0, 0, 0);
                acc[gt][tt][1] = __builtin_amdgcn_mfma_f32_16x16x32_bf16(af[tt], b1, acc[gt][tt][1], 0, 0, 0);
            }
        }
    }

    int oc0 = g * 32 + lo, oc1 = oc0 + 16;
    float gi0 = g_i[oc0], gi1 = g_i[oc1], bi0 = b_i[oc0], bi1 = b_i[oc1];
    float gg0 = g_g[oc0], gg1 = g_g[oc1], bg0 = b_g[oc0], bg1 = b_g[oc1];
    float go0 = g_o[oc0], go1 = g_o[oc1], bo0 = b_o[oc0], bo1 = b_o[oc1];

    #pragma unroll
    for (int tt = 0; tt < 3; tt++) {
        if (tv[tt]) {
            int tile = tbase + tt;
            #pragma unroll
            for (int r = 0; r < 4; r++) {
                int p = tile * 16 + hi * 4 + r;
                #pragma unroll
                for (int ot = 0; ot < 2; ot++) {
                    float gi = ot ? gi1 : gi0, bi = ot ? bi1 : bi0;
                    float gg_ = ot ? gg1 : gg0, bg = ot ? bg1 : bg0;
                    float go = ot ? go1 : go0, bo = ot ? bo1 : bo0;
                    float iv = sigm(gi * acc[0][tt][ot][r] + bi);
                    float gv = tanh_fast(gg_ * acc[1][tt][ot][r] + bg);
                    float ov = sigm(go * acc[2][tt][ot][r] + bo);
                    int oc = g * 32 + ot * 16 + lo;
                    out[((size_t)n * CC + oc) * HWP + p] = ov * tanh_fast(iv * gv);
                }
            }
        }
    }
}

extern "C" void kernel_launch(void* const* d_in, const int* in_sizes, int n_in,
                              void* d_out, int out_size, void* d_ws, size_t ws_size,
                              hipStream_t stream) {
    const float* x_in = (const float*)d_in[0];
    const float* W_xi = (const float*)d_in[2];
    const float* Wq   = (const float*)d_in[3];
    const float* Wk   = (const float*)d_in[4];
    const float* Wv   = (const float*)d_in[5];
    const float* Wi_a = (const float*)d_in[6];
    const float* Wi_x = (const float*)d_in[7];
    const float* b_i  = (const float*)d_in[8];
    const float* g_i  = (const float*)d_in[9];
    const float* Wg_a = (const float*)d_in[14];
    const float* Wg_x = (const float*)d_in[15];
    const float* b_g  = (const float*)d_in[16];
    const float* g_g  = (const float*)d_in[17];
    const float* Wo_a = (const float*)d_in[18];
    const float* Wo_x = (const float*)d_in[19];
    const float* b_o  = (const float*)d_in[20];
    const float* g_o  = (const float*)d_in[21];
    const float* tau  = (const float*)d_in[22];
    float* out = (float*)d_out;

    char* ws = (char*)d_ws;
    const size_t ab_bytes  = (size_t)NB * GG * HWP * 32 * 2;
    const size_t qb_bytes  = (size_t)NB * GG * HWP * 32 * 2;
    const size_t kb_bytes  = (size_t)NB * GG * KB_D * 32 * 2;
    const size_t vbt_bytes = (size_t)NB * GG * VBT_NG * 2;
    const size_t xpb_bytes = (size_t)NB * GG * PPN * 32 * 2;
    const size_t wpk_bytes = (size_t)NPACK * 2;
    short* a_b = (short*)ws;                      ws += ab_bytes;
    short* qbv = (short*)ws;                      ws += qb_bytes;
    short* kbv = (short*)ws;                      ws += kb_bytes;
    short* vbt = (short*)ws;                      ws += vbt_bytes;
    short* xpb = (short*)ws;                      ws += xpb_bytes;
    short* wpk = (short*)ws;                      ws += wpk_bytes;
    short* wgpk = (short*)ws;

    dim3 blk(256);
    k_initP<<<dim3(NINITB + NPROJB), blk, 0, stream>>>(x_in, W_xi, Wq, Wk, Wv, tau,
                                                       Wi_x, Wi_a, Wg_x, Wg_a, Wo_x, Wo_a,
                                                       wpk, wgpk, kbv, vbt, xpb);
    k_qkvM<<<dim3(64, 7, 3), blk, 0, stream>>>(xpb, wpk, qbv, kbv, vbt);
    k_attn<<<dim3(64, 11), dim3(512), 0, stream>>>(qbv, kbv, vbt, a_b);
    k_gatesM<<<dim3(64, 7), blk, 0, stream>>>(xpb, a_b, wgpk,
                                              b_i, g_i, b_g, g_g, b_o, g_o,
                                              out);
}

// Round 16
// 85.450 us; speedup vs baseline: 1.2341x; 1.2341x over previous
//
#include <hip/hip_runtime.h>
#include <math.h>

typedef __attribute__((ext_vector_type(8))) short short8;
typedef __attribute__((ext_vector_type(4))) float f32x4;

#define NB   8
#define CIN  128
#define CC   256
#define GG   8
#define CGR  32
#define HH   36
#define WW   36
#define HWP  1296
#define DHH  34
#define DD   1156

#define PPW  38
#define PPN  1444

#define KB_D 1216
#define VBT_STRIDE 1216
#define VBT_NG     (32 * VBT_STRIDE)

#define AW   8
#define KS   40
#define VS   72
#define WS2  72

#define NPACK  (3 * 8 * 9 * 32 * 32)      // 221184
#define NPACKG (8 * 3 * 10 * 32 * 32)     // 245760
#define NPACKX (2 * 4 * 128 * 32)         // 32768 (W_xi B-frag pack)
#define ZPERNG (2432 + 2304 + 1920 + 1920)
#define NZERO  (64 * ZPERNG)              // 548864
#define NINIT  (NPACK + NPACKG + NPACKX + NZERO)  // 1048576
#define NINITB (NINIT / 256)              // 4096

__device__ inline short f2bf(float f) {
    union { float f; unsigned u; } v; v.f = f;
    unsigned r = v.u + 0x7fffu + ((v.u >> 16) & 1u);
    return (short)(r >> 16);
}

__device__ inline float sigm(float z) { return 1.f / (1.f + __expf(-z)); }
__device__ inline float tanh_fast(float z) { return 2.f / (1.f + __expf(-2.f * z)) - 1.f; }

// ---------------- init: all weight packs + pad zeroing ----------------
__global__ __launch_bounds__(256) void k_init(const float* __restrict__ W_xi,
                                              const float* __restrict__ Wq,
                                              const float* __restrict__ Wk,
                                              const float* __restrict__ Wv,
                                              const float* __restrict__ tau,
                                              const float* __restrict__ Wi_x, const float* __restrict__ Wi_a,
                                              const float* __restrict__ Wg_x, const float* __restrict__ Wg_a,
                                              const float* __restrict__ Wo_x, const float* __restrict__ Wo_a,
                                              short* __restrict__ wpk,
                                              short* __restrict__ wgpk,
                                              short* __restrict__ wxp,
                                              short* __restrict__ kb,
                                              short* __restrict__ vbt,
                                              short* __restrict__ xpb) {
    int idx = blockIdx.x * 256 + threadIdx.x;
    if (idx < NPACK) {
        int cpos = idx & 31;
        int oc   = (idx >> 5) & 31;
        int tap  = (idx >> 10) % 9;
        int cg   = idx / 9216;
        int conv = cg >> 3, g = cg & 7;
        int ci = cpos ^ ((oc & 3) << 3);
        const float* W = (conv == 0) ? Wq : (conv == 1) ? Wk : Wv;
        float v = W[(size_t)(g * 32 + oc) * 576 + ci * 9 + tap];
        if (conv == 0) v *= tau[g] * 1.4426950408889634f;
        wpk[idx] = f2bf(v);
        return;
    }
    idx -= NPACK;
    if (idx < NPACKG) {
        int cpos = idx & 31;
        int oc   = (idx >> 5) & 31;
        int tap  = (idx >> 10) % 10;
        int gg_  = idx / 10240;
        int g    = gg_ / 3, gate = gg_ % 3;
        int ci = cpos ^ ((oc & 3) << 3);
        const float* Wx = (gate == 0) ? Wi_x : (gate == 1) ? Wg_x : Wo_x;
        const float* Wa = (gate == 0) ? Wi_a : (gate == 1) ? Wg_a : Wo_a;
        float v = (tap < 9) ? Wx[(size_t)(g * 32 + oc) * 576 + ci * 9 + tap]
                            : Wa[(g * 32 + oc) * 32 + ci];
        wgpk[idx] = f2bf(v);
        return;
    }
    idx -= NPACKG;
    if (idx < NPACKX) {
        // wxp[ohalf][sc][oc'][cpos] : B-frag pack of W_xi (bf16, involutive ci-swizzle)
        int cpos = idx & 31;
        int ocp  = (idx >> 5) & 127;
        int sc   = (idx >> 12) & 3;
        int oh   = idx >> 14;
        int ci = sc * 32 + (cpos ^ ((ocp & 3) << 3));
        wxp[idx] = f2bf(W_xi[(size_t)(oh * 128 + ocp) * CIN + ci]);
        return;
    }
    idx -= NPACKX;
    if (idx >= NZERO) return;
    int ng = idx / ZPERNG;
    int r  = idx % ZPERNG;
    if (r < 2432) {
        int row = (r < 1216) ? 0 : 37;
        int off = (r < 1216) ? r : r - 1216;
        xpb[(size_t)ng * PPN * 32 + (size_t)row * 1216 + off] = 0;
    } else if (r < 4736) {
        int r2 = r - 2432;
        int row = 1 + r2 / 64;
        int rem = r2 % 64;
        int col = (rem < 32) ? 0 : 37;
        int ch = rem & 31;
        xpb[(size_t)ng * PPN * 32 + (size_t)(row * PPW + col) * 32 + ch] = 0;
    } else if (r < 6656) {
        int r3 = r - 4736;
        kb[(size_t)ng * KB_D * 32 + (size_t)DD * 32 + r3] = 0;
    } else {
        int r4 = r - 6656;
        int c = r4 / 60, d = r4 % 60;
        vbt[(size_t)ng * VBT_NG + (size_t)c * VBT_STRIDE + DD + d] = 0;
    }
}

// ---------------- MFMA 1x1 projection: xpb = bf16(W_xi * x_in) ----------------
// Clone of the k_qkvM loop nest. Block: (pxchunk of 4 tiles, oc-half of 128, n).
// A-frags built per-lane from x_in scalar loads (+bf16 cvt); B staged 32 KB in LDS.
__global__ __launch_bounds__(256) void k_projM(const float* __restrict__ x_in,
                                               const short* __restrict__ wxp,
                                               short* __restrict__ xpb) {
    __shared__ short b_lds[4 * 128 * 32];
    int chunk = blockIdx.x, oh = blockIdx.y, n = blockIdx.z;

    const short* wsrc = wxp + (size_t)oh * 16384;
    for (int idx = threadIdx.x; idx < 2048; idx += 256)
        *(uint4*)(&b_lds[idx * 8]) = *(const uint4*)(wsrc + idx * 8);
    __syncthreads();

    int tid = threadIdx.x;
    int wv = tid >> 6, ln = tid & 63, lo = ln & 15, hi = ln >> 4;
    int tile = chunk * 4 + wv;
    bool tv = (tile < 81);
    int swz = (hi * 8) ^ ((lo & 3) << 3);

    short8 af[4];
    if (tv) {
        int px = tile * 16 + lo;
        const float* xb = x_in + (size_t)n * CIN * HWP + px;
        #pragma unroll
        for (int sc = 0; sc < 4; sc++) {
            short tmp[8];
            #pragma unroll
            for (int j2 = 0; j2 < 8; j2++)
                tmp[j2] = f2bf(xb[(size_t)(sc * 32 + hi * 8 + j2) * HWP]);
            af[sc] = *(short8*)tmp;
        }

        f32x4 acc[8];
        #pragma unroll
        for (int ot = 0; ot < 8; ot++) acc[ot] = (f32x4){0.f, 0.f, 0.f, 0.f};
        #pragma unroll
        for (int sc = 0; sc < 4; sc++) {
            #pragma unroll
            for (int ot = 0; ot < 8; ot++) {
                short8 bf = *(const short8*)(&b_lds[sc * 4096 + (ot * 16 + lo) * 32 + swz]);
                acc[ot] = __builtin_amdgcn_mfma_f32_16x16x32_bf16(af[sc], bf, acc[ot], 0, 0, 0);
            }
        }

        #pragma unroll
        for (int ot = 0; ot < 8; ot++) {
            int ocg = oh * 128 + ot * 16 + lo;
            int g = ocg >> 5, c = ocg & 31;
            short* xgw = xpb + (size_t)(n * GG + g) * PPN * 32 + c;
            #pragma unroll
            for (int r = 0; r < 4; r++) {
                int p = tile * 16 + hi * 4 + r;
                int y = p / 36, xx = p - y * 36;
                xgw[(size_t)((y + 1) * PPW + xx + 1) * 32] = f2bf(acc[ot][r]);
            }
        }
    }
}

// ---------------- MFMA grouped 3x3 conv for q/k/v (verbatim round-12, proven) ----------------
__global__ __launch_bounds__(256) void k_qkvM(const short* __restrict__ xpb,
                                              const short* __restrict__ wpk,
                                              short* __restrict__ qb,
                                              short* __restrict__ kb,
                                              short* __restrict__ vbt) {
    __shared__ short w_lds[9 * 32 * 32];
    int ng = blockIdx.x, chunk = blockIdx.y, conv = blockIdx.z;
    int n = ng >> 3, g = ng & 7;

    const short* wsrc = wpk + (size_t)(conv * 8 + g) * 9216;
    for (int idx = threadIdx.x; idx < 1152; idx += 256)
        *(uint4*)(&w_lds[idx * 8]) = *(const uint4*)(wsrc + idx * 8);
    __syncthreads();

    int tid = threadIdx.x;
    int wv = tid >> 6, ln = tid & 63, lo = ln & 15, hi = ln >> 4;
    const short* xg = xpb + (size_t)(n * GG + g) * PPN * 32;
    int swz = (hi * 8) ^ ((lo & 3) << 3);

    f32x4 acc[3][2];
    #pragma unroll
    for (int tt = 0; tt < 3; tt++)
        #pragma unroll
        for (int ot = 0; ot < 2; ot++) acc[tt][ot] = (f32x4){0.f, 0.f, 0.f, 0.f};

    int tbase = chunk * 12 + wv * 3;
    #pragma unroll
    for (int tt = 0; tt < 3; tt++) {
        int tile = tbase + tt;
        if (tile < 81) {
            int p = tile * 16 + lo;
            int y = p / 36, xx = p - y * 36;
            const short* ab = xg + ((size_t)((y + 1) * PPW + xx + 1) * 32 + hi * 8);
            #pragma unroll
            for (int tap = 0; tap < 9; tap++) {
                int toff = (tap / 3 - 1) * PPW + (tap % 3 - 1);
                short8 af = *(const short8*)(ab + toff * 32);
                short8 b0 = *(const short8*)(&w_lds[tap * 1024 + lo * 32 + swz]);
                short8 b1 = *(const short8*)(&w_lds[tap * 1024 + (16 + lo) * 32 + swz]);
                acc[tt][0] = __builtin_amdgcn_mfma_f32_16x16x32_bf16(af, b0, acc[tt][0], 0, 0, 0);
                acc[tt][1] = __builtin_amdgcn_mfma_f32_16x16x32_bf16(af, b1, acc[tt][1], 0, 0, 0);
            }
        }
    }

    size_t bofs = (size_t)n * GG + g;
    #pragma unroll
    for (int tt = 0; tt < 3; tt++) {
        int tile = tbase + tt;
        if (tile < 81) {
            #pragma unroll
            for (int r = 0; r < 4; r++) {
                int p = tile * 16 + hi * 4 + r;
                int y = p / 36, xx = p - y * 36;
                #pragma unroll
                for (int ot = 0; ot < 2; ot++) {
                    short val = f2bf(acc[tt][ot][r]);
                    int oc = ot * 16 + lo;
                    if (conv == 0) {
                        qb[bofs * ((size_t)HWP * 32) + (size_t)p * 32 + oc] = val;
                    } else if ((unsigned)(y - 1) < DHH && (unsigned)(xx - 1) < DHH) {
                        int d = (y - 1) * DHH + (xx - 1);
                        if (conv == 1) kb[bofs * ((size_t)KB_D * 32) + (size_t)d * 32 + oc] = val;
                        else           vbt[bofs * (size_t)VBT_NG + (size_t)oc * VBT_STRIDE + d] = val;
                    }
                }
            }
        }
    }
}

// ---------------- MFMA attention: 8 waves/block, double-buffered LDS staging ----------------
// (verbatim round-9 kernel — known good)
__global__ __launch_bounds__(512) void k_attn(const short* __restrict__ qb,
                                              const short* __restrict__ kb,
                                              const short* __restrict__ vbt,
                                              short* __restrict__ a_b) {
    __shared__ short k_s[2][64 * KS];
    __shared__ short v_s[2][32 * VS];
    __shared__ short w_s[AW][16 * WS2];

    int ng = blockIdx.x, qc = blockIdx.y;
    int tid = threadIdx.x;
    int wv = tid >> 6, ln = tid & 63;
    int lo = ln & 15, hi = ln >> 4;
    const short* qg = qb + (size_t)ng * HWP * 32;
    const short* kg = kb + (size_t)ng * KB_D * 32;
    const short* vg = vbt + (size_t)ng * VBT_NG;
    short* ag = a_b + (size_t)ng * HWP * 32;

    int tile = qc * AW + wv;
    bool tv = (tile < 81);
    short8 qf = (short8){0,0,0,0,0,0,0,0};
    if (tv) qf = *(const short8*)(qg + (size_t)(tile * 16 + lo) * 32 + hi * 8);

    int kd = tid >> 2, kco = (tid & 3) << 3;
    int vc = (tid >> 3) & 31, vdo = (tid & 7) << 3;
    bool isK = (tid < 256);

    f32x4 oacc[2];
    oacc[0] = (f32x4){0.f, 0.f, 0.f, 0.f};
    oacc[1] = (f32x4){0.f, 0.f, 0.f, 0.f};
    float rs = 0.f;
    const f32x4 fz = {0.f, 0.f, 0.f, 0.f};

    {
        uint4 s0;
        if (isK) s0 = *(const uint4*)(kg + (size_t)kd * 32 + kco);
        else     s0 = *(const uint4*)(vg + (size_t)vc * VBT_STRIDE + vdo);
        if (isK) *(uint4*)(&k_s[0][kd * KS + kco]) = s0;
        else     *(uint4*)(&v_s[0][vc * VS + vdo]) = s0;
    }
    __syncthreads();

    for (int dt = 0; dt < 19; dt++) {
        int cur = dt & 1, nxt = cur ^ 1;
        uint4 nreg;
        if (dt < 18) {
            int d1 = (dt + 1) << 6;
            if (isK) nreg = *(const uint4*)(kg + (size_t)(d1 + kd) * 32 + kco);
            else     nreg = *(const uint4*)(vg + (size_t)vc * VBT_STRIDE + d1 + vdo);
        }

        if (tv) {
            #pragma unroll
            for (int sub = 0; sub < 4; sub++) {
                short8 kf = *(const short8*)(&k_s[cur][(sub * 16 + lo) * KS + hi * 8]);
                f32x4 s2 = __builtin_amdgcn_mfma_f32_16x16x32_bf16(kf, qf, fz, 0, 0, 0);
                float w0, w1, w2, w3;
                asm("v_exp_f32 %0, %1" : "=v"(w0) : "v"(s2[0]));
                asm("v_exp_f32 %0, %1" : "=v"(w1) : "v"(s2[1]));
                asm("v_exp_f32 %0, %1" : "=v"(w2) : "v"(s2[2]));
                asm("v_exp_f32 %0, %1" : "=v"(w3) : "v"(s2[3]));
                rs += (w0 + w1) + (w2 + w3);
                unsigned p01, p23;
                asm("v_cvt_pk_bf16_f32 %0, %1, %2" : "=v"(p01) : "v"(w0), "v"(w1));
                asm("v_cvt_pk_bf16_f32 %0, %1, %2" : "=v"(p23) : "v"(w2), "v"(w3));
                uint2 pk; pk.x = p01; pk.y = p23;
                *(uint2*)(&w_s[wv][lo * WS2 + sub * 16 + hi * 4]) = pk;
            }
            #pragma unroll
            for (int h = 0; h < 2; h++) {
                short8 af = *(const short8*)(&w_s[wv][lo * WS2 + h * 32 + hi * 8]);
                #pragma unroll
                for (int cs = 0; cs < 2; cs++) {
                    short8 vf = *(const short8*)(&v_s[cur][(cs * 16 + lo) * VS + h * 32 + hi * 8]);
                    oacc[cs] = __builtin_amdgcn_mfma_f32_16x16x32_bf16(af, vf, oacc[cs], 0, 0, 0);
                }
            }
        }

        if (dt < 18) {
            if (isK) *(uint4*)(&k_s[nxt][kd * KS + kco]) = nreg;
            else     *(uint4*)(&v_s[nxt][vc * VS + vdo]) = nreg;
        }
        __syncthreads();
    }

    float s = rs;
    s += __shfl_xor(s, 16);
    s += __shfl_xor(s, 32);
    float inv = 1.f / (s - 60.f);

    if (tv) {
        #pragma unroll
        for (int r = 0; r < 4; r++) {
            float iv = __shfl(inv, hi * 4 + r);
            int row = tile * 16 + hi * 4 + r;
            #pragma unroll
            for (int cs = 0; cs < 2; cs++)
                ag[(size_t)row * 32 + cs * 16 + lo] = f2bf(oacc[cs][r] * iv);
        }
    }
}

// ---------------- MFMA gates: i/g/o (f dead) + fused LSTM epilogue ----------------
__global__ __launch_bounds__(256) void k_gatesM(const short* __restrict__ xpb,
                                                const short* __restrict__ a_b,
                                                const short* __restrict__ wgpk,
                                                const float* __restrict__ b_i, const float* __restrict__ g_i,
                                                const float* __restrict__ b_g, const float* __restrict__ g_g,
                                                const float* __restrict__ b_o, const float* __restrict__ g_o,
                                                float* __restrict__ out) {
    __shared__ short w_lds[3 * 10 * 32 * 32];
    int ng = blockIdx.x, chunk = blockIdx.y;
    int n = ng >> 3, g = ng & 7;

    const short* wsrc = wgpk + (size_t)g * 30720;
    for (int idx = threadIdx.x; idx < 3840; idx += 256)
        *(uint4*)(&w_lds[idx * 8]) = *(const uint4*)(wsrc + idx * 8);
    __syncthreads();

    int tid = threadIdx.x;
    int wv = tid >> 6, ln = tid & 63, lo = ln & 15, hi = ln >> 4;
    const short* xg = xpb + (size_t)(n * GG + g) * PPN * 32;
    const short* ab_a = a_b + (size_t)(n * GG + g) * HWP * 32;
    int swz = (hi * 8) ^ ((lo & 3) << 3);

    f32x4 acc[3][3][2];
    #pragma unroll
    for (int gt = 0; gt < 3; gt++)
        #pragma unroll
        for (int tt = 0; tt < 3; tt++)
            #pragma unroll
            for (int ot = 0; ot < 2; ot++) acc[gt][tt][ot] = (f32x4){0.f, 0.f, 0.f, 0.f};

    int tbase = chunk * 12 + wv * 3;
    bool tv[3];
    int pbase[3];
    #pragma unroll
    for (int tt = 0; tt < 3; tt++) {
        int tile = tbase + tt;
        tv[tt] = (tile < 81);
        int p = tile * 16 + lo;
        int y = p / 36, xx = p - y * 36;
        pbase[tt] = ((y + 1) * PPW + xx + 1) * 32 + hi * 8;
    }

    #pragma unroll
    for (int tap = 0; tap < 9; tap++) {
        int toff = (tap / 3 - 1) * PPW + (tap % 3 - 1);
        short8 af[3];
        #pragma unroll
        for (int tt = 0; tt < 3; tt++) {
            af[tt] = (short8){0,0,0,0,0,0,0,0};
            if (tv[tt]) af[tt] = *(const short8*)(xg + pbase[tt] + toff * 32);
        }
        #pragma unroll
        for (int gt = 0; gt < 3; gt++) {
            const short* wl = &w_lds[(gt * 10 + tap) * 1024];
            short8 b0 = *(const short8*)(&wl[lo * 32 + swz]);
            short8 b1 = *(const short8*)(&wl[(16 + lo) * 32 + swz]);
            #pragma unroll
            for (int tt = 0; tt < 3; tt++) {
                acc[gt][tt][0] = __builtin_amdgcn_mfma_f32_16x16x32_bf16(af[tt], b0, acc[gt][tt][0], 0, 0, 0);
                acc[gt][tt][1] = __builtin_amdgcn_mfma_f32_16x16x32_bf16(af[tt], b1, acc[gt][tt][1], 0, 0, 0);
            }
        }
    }
    {
        short8 af[3];
        #pragma unroll
        for (int tt = 0; tt < 3; tt++) {
            af[tt] = (short8){0,0,0,0,0,0,0,0};
            if (tv[tt]) af[tt] = *(const short8*)(ab_a + (size_t)((tbase + tt) * 16 + lo) * 32 + hi * 8);
        }
        #pragma unroll
        for (int gt = 0; gt < 3; gt++) {
            const short* wl = &w_lds[(gt * 10 + 9) * 1024];
            short8 b0 = *(const short8*)(&wl[lo * 32 + swz]);
            short8 b1 = *(const short8*)(&wl[(16 + lo) * 32 + swz]);
            #pragma unroll
            for (int tt = 0; tt < 3; tt++) {
                acc[gt][tt][0] = __builtin_amdgcn_mfma_f32_16x16x32_bf16(af[tt], b0, acc[gt][tt][0], 0, 0, 0);
                acc[gt][tt][1] = __builtin_amdgcn_mfma_f32_16x16x32_bf16(af[tt], b1, acc[gt][tt][1], 0, 0, 0);
            }
        }
    }

    int oc0 = g * 32 + lo, oc1 = oc0 + 16;
    float gi0 = g_i[oc0], gi1 = g_i[oc1], bi0 = b_i[oc0], bi1 = b_i[oc1];
    float gg0 = g_g[oc0], gg1 = g_g[oc1], bg0 = b_g[oc0], bg1 = b_g[oc1];
    float go0 = g_o[oc0], go1 = g_o[oc1], bo0 = b_o[oc0], bo1 = b_o[oc1];

    #pragma unroll
    for (int tt = 0; tt < 3; tt++) {
        if (tv[tt]) {
            int tile = tbase + tt;
            #pragma unroll
            for (int r = 0; r < 4; r++) {
                int p = tile * 16 + hi * 4 + r;
                #pragma unroll
                for (int ot = 0; ot < 2; ot++) {
                    float gi = ot ? gi1 : gi0, bi = ot ? bi1 : bi0;
                    float gg_ = ot ? gg1 : gg0, bg = ot ? bg1 : bg0;
                    float go = ot ? go1 : go0, bo = ot ? bo1 : bo0;
                    float iv = sigm(gi * acc[0][tt][ot][r] + bi);
                    float gv = tanh_fast(gg_ * acc[1][tt][ot][r] + bg);
                    float ov = sigm(go * acc[2][tt][ot][r] + bo);
                    int oc = g * 32 + ot * 16 + lo;
                    out[((size_t)n * CC + oc) * HWP + p] = ov * tanh_fast(iv * gv);
                }
            }
        }
    }
}

extern "C" void kernel_launch(void* const* d_in, const int* in_sizes, int n_in,
                              void* d_out, int out_size, void* d_ws, size_t ws_size,
                              hipStream_t stream) {
    const float* x_in = (const float*)d_in[0];
    const float* W_xi = (const float*)d_in[2];
    const float* Wq   = (const float*)d_in[3];
    const float* Wk   = (const float*)d_in[4];
    const float* Wv   = (const float*)d_in[5];
    const float* Wi_a = (const float*)d_in[6];
    const float* Wi_x = (const float*)d_in[7];
    const float* b_i  = (const float*)d_in[8];
    const float* g_i  = (const float*)d_in[9];
    const float* Wg_a = (const float*)d_in[14];
    const float* Wg_x = (const float*)d_in[15];
    const float* b_g  = (const float*)d_in[16];
    const float* g_g  = (const float*)d_in[17];
    const float* Wo_a = (const float*)d_in[18];
    const float* Wo_x = (const float*)d_in[19];
    const float* b_o  = (const float*)d_in[20];
    const float* g_o  = (const float*)d_in[21];
    const float* tau  = (const float*)d_in[22];
    float* out = (float*)d_out;

    char* ws = (char*)d_ws;
    const size_t ab_bytes  = (size_t)NB * GG * HWP * 32 * 2;
    const size_t qb_bytes  = (size_t)NB * GG * HWP * 32 * 2;
    const size_t kb_bytes  = (size_t)NB * GG * KB_D * 32 * 2;
    const size_t vbt_bytes = (size_t)NB * GG * VBT_NG * 2;
    const size_t xpb_bytes = (size_t)NB * GG * PPN * 32 * 2;
    const size_t wpk_bytes = (size_t)NPACK * 2;
    const size_t wgpk_bytes = (size_t)NPACKG * 2;
    short* a_b = (short*)ws;                      ws += ab_bytes;
    short* qbv = (short*)ws;                      ws += qb_bytes;
    short* kbv = (short*)ws;                      ws += kb_bytes;
    short* vbt = (short*)ws;                      ws += vbt_bytes;
    short* xpb = (short*)ws;                      ws += xpb_bytes;
    short* wpk = (short*)ws;                      ws += wpk_bytes;
    short* wgpk = (short*)ws;                     ws += wgpk_bytes;
    short* wxp = (short*)ws;

    dim3 blk(256);
    k_init<<<dim3(NINITB), blk, 0, stream>>>(W_xi, Wq, Wk, Wv, tau,
                                             Wi_x, Wi_a, Wg_x, Wg_a, Wo_x, Wo_a,
                                             wpk, wgpk, wxp, kbv, vbt, xpb);
    k_projM<<<dim3(21, 2, NB), blk, 0, stream>>>(x_in, wxp, xpb);
    k_qkvM<<<dim3(64, 7, 3), blk, 0, stream>>>(xpb, wpk, qbv, kbv, vbt);
    k_attn<<<dim3(64, 11), dim3(512), 0, stream>>>(qbv, kbv, vbt, a_b);
    k_gatesM<<<dim3(64, 7), blk, 0, stream>>>(xpb, a_b, wgpk,
                                              b_i, g_i, b_g, g_g, b_o, g_o,
                                              out);
}

// Round 17
// 83.356 us; speedup vs baseline: 1.2651x; 1.0251x over previous
//
#include <hip/hip_runtime.h>
#include <math.h>

typedef __attribute__((ext_vector_type(8))) short short8;
typedef __attribute__((ext_vector_type(4))) float f32x4;

#define NB   8
#define CIN  128
#define CC   256
#define GG   8
#define CGR  32
#define HH   36
#define WW   36
#define HWP  1296
#define DHH  34
#define DD   1156

#define PPW  38
#define PPN  1444

#define KB_D 1216
#define VBT_STRIDE 1216
#define VBT_NG     (32 * VBT_STRIDE)

#define AW   8
#define KS   40
#define VS   72
#define WS2  72

#define NPACK  (3 * 8 * 9 * 32 * 32)      // 221184
#define NPACKG (8 * 3 * 10 * 32 * 32)     // 245760
#define NPACKX (2 * 4 * 128 * 32)         // 32768
#define ZPERNG (2432 + 2304 + 1920 + 1920)
#define NZERO  (64 * ZPERNG)              // 548864
#define NINIT  (NPACK + NPACKG + NPACKX + NZERO)  // 1048576
#define NINITB (NINIT / 256)              // 4096

__device__ inline short f2bf(float f) {
    union { float f; unsigned u; } v; v.f = f;
    unsigned r = v.u + 0x7fffu + ((v.u >> 16) & 1u);
    return (short)(r >> 16);
}

__device__ inline float sigm(float z) { return 1.f / (1.f + __expf(-z)); }
__device__ inline float tanh_fast(float z) { return 2.f / (1.f + __expf(-2.f * z)) - 1.f; }

// ---------------- init: all weight packs + pad zeroing ----------------
__global__ __launch_bounds__(256) void k_init(const float* __restrict__ W_xi,
                                              const float* __restrict__ Wq,
                                              const float* __restrict__ Wk,
                                              const float* __restrict__ Wv,
                                              const float* __restrict__ tau,
                                              const float* __restrict__ Wi_x, const float* __restrict__ Wi_a,
                                              const float* __restrict__ Wg_x, const float* __restrict__ Wg_a,
                                              const float* __restrict__ Wo_x, const float* __restrict__ Wo_a,
                                              short* __restrict__ wpk,
                                              short* __restrict__ wgpk,
                                              short* __restrict__ wxp,
                                              short* __restrict__ kb,
                                              short* __restrict__ vbt,
                                              short* __restrict__ xpb) {
    int idx = blockIdx.x * 256 + threadIdx.x;
    if (idx < NPACK) {
        int cpos = idx & 31;
        int oc   = (idx >> 5) & 31;
        int tap  = (idx >> 10) % 9;
        int cg   = idx / 9216;
        int conv = cg >> 3, g = cg & 7;
        int ci = cpos ^ ((oc & 3) << 3);
        const float* W = (conv == 0) ? Wq : (conv == 1) ? Wk : Wv;
        float v = W[(size_t)(g * 32 + oc) * 576 + ci * 9 + tap];
        if (conv == 0) v *= tau[g] * 1.4426950408889634f;
        wpk[idx] = f2bf(v);
        return;
    }
    idx -= NPACK;
    if (idx < NPACKG) {
        int cpos = idx & 31;
        int oc   = (idx >> 5) & 31;
        int tap  = (idx >> 10) % 10;
        int gg_  = idx / 10240;
        int g    = gg_ / 3, gate = gg_ % 3;
        int ci = cpos ^ ((oc & 3) << 3);
        const float* Wx = (gate == 0) ? Wi_x : (gate == 1) ? Wg_x : Wo_x;
        const float* Wa = (gate == 0) ? Wi_a : (gate == 1) ? Wg_a : Wo_a;
        float v = (tap < 9) ? Wx[(size_t)(g * 32 + oc) * 576 + ci * 9 + tap]
                            : Wa[(g * 32 + oc) * 32 + ci];
        wgpk[idx] = f2bf(v);
        return;
    }
    idx -= NPACKG;
    if (idx < NPACKX) {
        int cpos = idx & 31;
        int ocp  = (idx >> 5) & 127;
        int sc   = (idx >> 12) & 3;
        int oh   = idx >> 14;
        int ci = sc * 32 + (cpos ^ ((ocp & 3) << 3));
        wxp[idx] = f2bf(W_xi[(size_t)(oh * 128 + ocp) * CIN + ci]);
        return;
    }
    idx -= NPACKX;
    if (idx >= NZERO) return;
    int ng = idx / ZPERNG;
    int r  = idx % ZPERNG;
    if (r < 2432) {
        int row = (r < 1216) ? 0 : 37;
        int off = (r < 1216) ? r : r - 1216;
        xpb[(size_t)ng * PPN * 32 + (size_t)row * 1216 + off] = 0;
    } else if (r < 4736) {
        int r2 = r - 2432;
        int row = 1 + r2 / 64;
        int rem = r2 % 64;
        int col = (rem < 32) ? 0 : 37;
        int ch = rem & 31;
        xpb[(size_t)ng * PPN * 32 + (size_t)(row * PPW + col) * 32 + ch] = 0;
    } else if (r < 6656) {
        int r3 = r - 4736;
        kb[(size_t)ng * KB_D * 32 + (size_t)DD * 32 + r3] = 0;
    } else {
        int r4 = r - 6656;
        int c = r4 / 60, d = r4 % 60;
        vbt[(size_t)ng * VBT_NG + (size_t)c * VBT_STRIDE + DD + d] = 0;
    }
}

// ---------------- MFMA 1x1 projection (verbatim round-16, proven) ----------------
__global__ __launch_bounds__(256) void k_projM(const float* __restrict__ x_in,
                                               const short* __restrict__ wxp,
                                               short* __restrict__ xpb) {
    __shared__ short b_lds[4 * 128 * 32];
    int chunk = blockIdx.x, oh = blockIdx.y, n = blockIdx.z;

    const short* wsrc = wxp + (size_t)oh * 16384;
    for (int idx = threadIdx.x; idx < 2048; idx += 256)
        *(uint4*)(&b_lds[idx * 8]) = *(const uint4*)(wsrc + idx * 8);
    __syncthreads();

    int tid = threadIdx.x;
    int wv = tid >> 6, ln = tid & 63, lo = ln & 15, hi = ln >> 4;
    int tile = chunk * 4 + wv;
    bool tv = (tile < 81);
    int swz = (hi * 8) ^ ((lo & 3) << 3);

    short8 af[4];
    if (tv) {
        int px = tile * 16 + lo;
        const float* xb = x_in + (size_t)n * CIN * HWP + px;
        #pragma unroll
        for (int sc = 0; sc < 4; sc++) {
            short tmp[8];
            #pragma unroll
            for (int j2 = 0; j2 < 8; j2++)
                tmp[j2] = f2bf(xb[(size_t)(sc * 32 + hi * 8 + j2) * HWP]);
            af[sc] = *(short8*)tmp;
        }

        f32x4 acc[8];
        #pragma unroll
        for (int ot = 0; ot < 8; ot++) acc[ot] = (f32x4){0.f, 0.f, 0.f, 0.f};
        #pragma unroll
        for (int sc = 0; sc < 4; sc++) {
            #pragma unroll
            for (int ot = 0; ot < 8; ot++) {
                short8 bf = *(const short8*)(&b_lds[sc * 4096 + (ot * 16 + lo) * 32 + swz]);
                acc[ot] = __builtin_amdgcn_mfma_f32_16x16x32_bf16(af[sc], bf, acc[ot], 0, 0, 0);
            }
        }

        #pragma unroll
        for (int ot = 0; ot < 8; ot++) {
            int ocg = oh * 128 + ot * 16 + lo;
            int g = ocg >> 5, c = ocg & 31;
            short* xgw = xpb + (size_t)(n * GG + g) * PPN * 32 + c;
            #pragma unroll
            for (int r = 0; r < 4; r++) {
                int p = tile * 16 + hi * 4 + r;
                int y = p / 36, xx = p - y * 36;
                xgw[(size_t)((y + 1) * PPW + xx + 1) * 32] = f2bf(acc[ot][r]);
            }
        }
    }
}

// ---------------- MFMA grouped 3x3 conv q/k/v: 512-thread blocks (8 waves, 24 tiles) ----------------
__global__ __launch_bounds__(512) void k_qkvM(const short* __restrict__ xpb,
                                              const short* __restrict__ wpk,
                                              short* __restrict__ qb,
                                              short* __restrict__ kb,
                                              short* __restrict__ vbt) {
    __shared__ short w_lds[9 * 32 * 32];
    int ng = blockIdx.x, chunk = blockIdx.y, conv = blockIdx.z;
    int n = ng >> 3, g = ng & 7;

    const short* wsrc = wpk + (size_t)(conv * 8 + g) * 9216;
    for (int idx = threadIdx.x; idx < 1152; idx += 512)
        *(uint4*)(&w_lds[idx * 8]) = *(const uint4*)(wsrc + idx * 8);
    __syncthreads();

    int tid = threadIdx.x;
    int wv = tid >> 6, ln = tid & 63, lo = ln & 15, hi = ln >> 4;
    const short* xg = xpb + (size_t)(n * GG + g) * PPN * 32;
    int swz = (hi * 8) ^ ((lo & 3) << 3);

    f32x4 acc[3][2];
    #pragma unroll
    for (int tt = 0; tt < 3; tt++)
        #pragma unroll
        for (int ot = 0; ot < 2; ot++) acc[tt][ot] = (f32x4){0.f, 0.f, 0.f, 0.f};

    int tbase = chunk * 24 + wv * 3;
    #pragma unroll
    for (int tt = 0; tt < 3; tt++) {
        int tile = tbase + tt;
        if (tile < 81) {
            int p = tile * 16 + lo;
            int y = p / 36, xx = p - y * 36;
            const short* ab = xg + ((size_t)((y + 1) * PPW + xx + 1) * 32 + hi * 8);
            #pragma unroll
            for (int tap = 0; tap < 9; tap++) {
                int toff = (tap / 3 - 1) * PPW + (tap % 3 - 1);
                short8 af = *(const short8*)(ab + toff * 32);
                short8 b0 = *(const short8*)(&w_lds[tap * 1024 + lo * 32 + swz]);
                short8 b1 = *(const short8*)(&w_lds[tap * 1024 + (16 + lo) * 32 + swz]);
                acc[tt][0] = __builtin_amdgcn_mfma_f32_16x16x32_bf16(af, b0, acc[tt][0], 0, 0, 0);
                acc[tt][1] = __builtin_amdgcn_mfma_f32_16x16x32_bf16(af, b1, acc[tt][1], 0, 0, 0);
            }
        }
    }

    size_t bofs = (size_t)n * GG + g;
    #pragma unroll
    for (int tt = 0; tt < 3; tt++) {
        int tile = tbase + tt;
        if (tile < 81) {
            #pragma unroll
            for (int r = 0; r < 4; r++) {
                int p = tile * 16 + hi * 4 + r;
                int y = p / 36, xx = p - y * 36;
                #pragma unroll
                for (int ot = 0; ot < 2; ot++) {
                    short val = f2bf(acc[tt][ot][r]);
                    int oc = ot * 16 + lo;
                    if (conv == 0) {
                        qb[bofs * ((size_t)HWP * 32) + (size_t)p * 32 + oc] = val;
                    } else if ((unsigned)(y - 1) < DHH && (unsigned)(xx - 1) < DHH) {
                        int d = (y - 1) * DHH + (xx - 1);
                        if (conv == 1) kb[bofs * ((size_t)KB_D * 32) + (size_t)d * 32 + oc] = val;
                        else           vbt[bofs * (size_t)VBT_NG + (size_t)oc * VBT_STRIDE + d] = val;
                    }
                }
            }
        }
    }
}

// ---------------- MFMA attention: 8 waves/block, double-buffered LDS staging ----------------
// (verbatim round-9 kernel — known good)
__global__ __launch_bounds__(512) void k_attn(const short* __restrict__ qb,
                                              const short* __restrict__ kb,
                                              const short* __restrict__ vbt,
                                              short* __restrict__ a_b) {
    __shared__ short k_s[2][64 * KS];
    __shared__ short v_s[2][32 * VS];
    __shared__ short w_s[AW][16 * WS2];

    int ng = blockIdx.x, qc = blockIdx.y;
    int tid = threadIdx.x;
    int wv = tid >> 6, ln = tid & 63;
    int lo = ln & 15, hi = ln >> 4;
    const short* qg = qb + (size_t)ng * HWP * 32;
    const short* kg = kb + (size_t)ng * KB_D * 32;
    const short* vg = vbt + (size_t)ng * VBT_NG;
    short* ag = a_b + (size_t)ng * HWP * 32;

    int tile = qc * AW + wv;
    bool tv = (tile < 81);
    short8 qf = (short8){0,0,0,0,0,0,0,0};
    if (tv) qf = *(const short8*)(qg + (size_t)(tile * 16 + lo) * 32 + hi * 8);

    int kd = tid >> 2, kco = (tid & 3) << 3;
    int vc = (tid >> 3) & 31, vdo = (tid & 7) << 3;
    bool isK = (tid < 256);

    f32x4 oacc[2];
    oacc[0] = (f32x4){0.f, 0.f, 0.f, 0.f};
    oacc[1] = (f32x4){0.f, 0.f, 0.f, 0.f};
    float rs = 0.f;
    const f32x4 fz = {0.f, 0.f, 0.f, 0.f};

    {
        uint4 s0;
        if (isK) s0 = *(const uint4*)(kg + (size_t)kd * 32 + kco);
        else     s0 = *(const uint4*)(vg + (size_t)vc * VBT_STRIDE + vdo);
        if (isK) *(uint4*)(&k_s[0][kd * KS + kco]) = s0;
        else     *(uint4*)(&v_s[0][vc * VS + vdo]) = s0;
    }
    __syncthreads();

    for (int dt = 0; dt < 19; dt++) {
        int cur = dt & 1, nxt = cur ^ 1;
        uint4 nreg;
        if (dt < 18) {
            int d1 = (dt + 1) << 6;
            if (isK) nreg = *(const uint4*)(kg + (size_t)(d1 + kd) * 32 + kco);
            else     nreg = *(const uint4*)(vg + (size_t)vc * VBT_STRIDE + d1 + vdo);
        }

        if (tv) {
            #pragma unroll
            for (int sub = 0; sub < 4; sub++) {
                short8 kf = *(const short8*)(&k_s[cur][(sub * 16 + lo) * KS + hi * 8]);
                f32x4 s2 = __builtin_amdgcn_mfma_f32_16x16x32_bf16(kf, qf, fz, 0, 0, 0);
                float w0, w1, w2, w3;
                asm("v_exp_f32 %0, %1" : "=v"(w0) : "v"(s2[0]));
                asm("v_exp_f32 %0, %1" : "=v"(w1) : "v"(s2[1]));
                asm("v_exp_f32 %0, %1" : "=v"(w2) : "v"(s2[2]));
                asm("v_exp_f32 %0, %1" : "=v"(w3) : "v"(s2[3]));
                rs += (w0 + w1) + (w2 + w3);
                unsigned p01, p23;
                asm("v_cvt_pk_bf16_f32 %0, %1, %2" : "=v"(p01) : "v"(w0), "v"(w1));
                asm("v_cvt_pk_bf16_f32 %0, %1, %2" : "=v"(p23) : "v"(w2), "v"(w3));
                uint2 pk; pk.x = p01; pk.y = p23;
                *(uint2*)(&w_s[wv][lo * WS2 + sub * 16 + hi * 4]) = pk;
            }
            #pragma unroll
            for (int h = 0; h < 2; h++) {
                short8 af = *(const short8*)(&w_s[wv][lo * WS2 + h * 32 + hi * 8]);
                #pragma unroll
                for (int cs = 0; cs < 2; cs++) {
                    short8 vf = *(const short8*)(&v_s[cur][(cs * 16 + lo) * VS + h * 32 + hi * 8]);
                    oacc[cs] = __builtin_amdgcn_mfma_f32_16x16x32_bf16(af, vf, oacc[cs], 0, 0, 0);
                }
            }
        }

        if (dt < 18) {
            if (isK) *(uint4*)(&k_s[nxt][kd * KS + kco]) = nreg;
            else     *(uint4*)(&v_s[nxt][vc * VS + vdo]) = nreg;
        }
        __syncthreads();
    }

    float s = rs;
    s += __shfl_xor(s, 16);
    s += __shfl_xor(s, 32);
    float inv = 1.f / (s - 60.f);

    if (tv) {
        #pragma unroll
        for (int r = 0; r < 4; r++) {
            float iv = __shfl(inv, hi * 4 + r);
            int row = tile * 16 + hi * 4 + r;
            #pragma unroll
            for (int cs = 0; cs < 2; cs++)
                ag[(size_t)row * 32 + cs * 16 + lo] = f2bf(oacc[cs][r] * iv);
        }
    }
}

// ---------------- MFMA gates: 512-thread blocks (8 waves, 24 tiles) ----------------
__global__ __launch_bounds__(512) void k_gatesM(const short* __restrict__ xpb,
                                                const short* __restrict__ a_b,
                                                const short* __restrict__ wgpk,
                                                const float* __restrict__ b_i, const float* __restrict__ g_i,
                                                const float* __restrict__ b_g, const float* __restrict__ g_g,
                                                const float* __restrict__ b_o, const float* __restrict__ g_o,
                                                float* __restrict__ out) {
    __shared__ short w_lds[3 * 10 * 32 * 32];
    int ng = blockIdx.x, chunk = blockIdx.y;
    int n = ng >> 3, g = ng & 7;

    const short* wsrc = wgpk + (size_t)g * 30720;
    for (int idx = threadIdx.x; idx < 3840; idx += 512)
        *(uint4*)(&w_lds[idx * 8]) = *(const uint4*)(wsrc + idx * 8);
    __syncthreads();

    int tid = threadIdx.x;
    int wv = tid >> 6, ln = tid & 63, lo = ln & 15, hi = ln >> 4;
    const short* xg = xpb + (size_t)(n * GG + g) * PPN * 32;
    const short* ab_a = a_b + (size_t)(n * GG + g) * HWP * 32;
    int swz = (hi * 8) ^ ((lo & 3) << 3);

    f32x4 acc[3][3][2];
    #pragma unroll
    for (int gt = 0; gt < 3; gt++)
        #pragma unroll
        for (int tt = 0; tt < 3; tt++)
            #pragma unroll
            for (int ot = 0; ot < 2; ot++) acc[gt][tt][ot] = (f32x4){0.f, 0.f, 0.f, 0.f};

    int tbase = chunk * 24 + wv * 3;
    bool tv[3];
    int pbase[3];
    #pragma unroll
    for (int tt = 0; tt < 3; tt++) {
        int tile = tbase + tt;
        tv[tt] = (tile < 81);
        int p = tile * 16 + lo;
        int y = p / 36, xx = p - y * 36;
        pbase[tt] = ((y + 1) * PPW + xx + 1) * 32 + hi * 8;
    }

    #pragma unroll
    for (int tap = 0; tap < 9; tap++) {
        int toff = (tap / 3 - 1) * PPW + (tap % 3 - 1);
        short8 af[3];
        #pragma unroll
        for (int tt = 0; tt < 3; tt++) {
            af[tt] = (short8){0,0,0,0,0,0,0,0};
            if (tv[tt]) af[tt] = *(const short8*)(xg + pbase[tt] + toff * 32);
        }
        #pragma unroll
        for (int gt = 0; gt < 3; gt++) {
            const short* wl = &w_lds[(gt * 10 + tap) * 1024];
            short8 b0 = *(const short8*)(&wl[lo * 32 + swz]);
            short8 b1 = *(const short8*)(&wl[(16 + lo) * 32 + swz]);
            #pragma unroll
            for (int tt = 0; tt < 3; tt++) {
                acc[gt][tt][0] = __builtin_amdgcn_mfma_f32_16x16x32_bf16(af[tt], b0, acc[gt][tt][0], 0, 0, 0);
                acc[gt][tt][1] = __builtin_amdgcn_mfma_f32_16x16x32_bf16(af[tt], b1, acc[gt][tt][1], 0, 0, 0);
            }
        }
    }
    {
        short8 af[3];
        #pragma unroll
        for (int tt = 0; tt < 3; tt++) {
            af[tt] = (short8){0,0,0,0,0,0,0,0};
            if (tv[tt]) af[tt] = *(const short8*)(ab_a + (size_t)((tbase + tt) * 16 + lo) * 32 + hi * 8);
        }
        #pragma unroll
        for (int gt = 0; gt < 3; gt++) {
            const short* wl = &w_lds[(gt * 10 + 9) * 1024];
            short8 b0 = *(const short8*)(&wl[lo * 32 + swz]);
            short8 b1 = *(const short8*)(&wl[(16 + lo) * 32 + swz]);
            #pragma unroll
            for (int tt = 0; tt < 3; tt++) {
                acc[gt][tt][0] = __builtin_amdgcn_mfma_f32_16x16x32_bf16(af[tt], b0, acc[gt][tt][0], 0, 0, 0);
                acc[gt][tt][1] = __builtin_amdgcn_mfma_f32_16x16x32_bf16(af[tt], b1, acc[gt][tt][1], 0, 0, 0);
            }
        }
    }

    int oc0 = g * 32 + lo, oc1 = oc0 + 16;
    float gi0 = g_i[oc0], gi1 = g_i[oc1], bi0 = b_i[oc0], bi1 = b_i[oc1];
    float gg0 = g_g[oc0], gg1 = g_g[oc1], bg0 = b_g[oc0], bg1 = b_g[oc1];
    float go0 = g_o[oc0], go1 = g_o[oc1], bo0 = b_o[oc0], bo1 = b_o[oc1];

    #pragma unroll
    for (int tt = 0; tt < 3; tt++) {
        if (tv[tt]) {
            int tile = tbase + tt;
            #pragma unroll
            for (int r = 0; r < 4; r++) {
                int p = tile * 16 + hi * 4 + r;
                #pragma unroll
                for (int ot = 0; ot < 2; ot++) {
                    float gi = ot ? gi1 : gi0, bi = ot ? bi1 : bi0;
                    float gg_ = ot ? gg1 : gg0, bg = ot ? bg1 : bg0;
                    float go = ot ? go1 : go0, bo = ot ? bo1 : bo0;
                    float iv = sigm(gi * acc[0][tt][ot][r] + bi);
                    float gv = tanh_fast(gg_ * acc[1][tt][ot][r] + bg);
                    float ov = sigm(go * acc[2][tt][ot][r] + bo);
                    int oc = g * 32 + ot * 16 + lo;
                    out[((size_t)n * CC + oc) * HWP + p] = ov * tanh_fast(iv * gv);
                }
            }
        }
    }
}

extern "C" void kernel_launch(void* const* d_in, const int* in_sizes, int n_in,
                              void* d_out, int out_size, void* d_ws, size_t ws_size,
                              hipStream_t stream) {
    const float* x_in = (const float*)d_in[0];
    const float* W_xi = (const float*)d_in[2];
    const float* Wq   = (const float*)d_in[3];
    const float* Wk   = (const float*)d_in[4];
    const float* Wv   = (const float*)d_in[5];
    const float* Wi_a = (const float*)d_in[6];
    const float* Wi_x = (const float*)d_in[7];
    const float* b_i  = (const float*)d_in[8];
    const float* g_i  = (const float*)d_in[9];
    const float* Wg_a = (const float*)d_in[14];
    const float* Wg_x = (const float*)d_in[15];
    const float* b_g  = (const float*)d_in[16];
    const float* g_g  = (const float*)d_in[17];
    const float* Wo_a = (const float*)d_in[18];
    const float* Wo_x = (const float*)d_in[19];
    const float* b_o  = (const float*)d_in[20];
    const float* g_o  = (const float*)d_in[21];
    const float* tau  = (const float*)d_in[22];
    float* out = (float*)d_out;

    char* ws = (char*)d_ws;
    const size_t ab_bytes  = (size_t)NB * GG * HWP * 32 * 2;
    const size_t qb_bytes  = (size_t)NB * GG * HWP * 32 * 2;
    const size_t kb_bytes  = (size_t)NB * GG * KB_D * 32 * 2;
    const size_t vbt_bytes = (size_t)NB * GG * VBT_NG * 2;
    const size_t xpb_bytes = (size_t)NB * GG * PPN * 32 * 2;
    const size_t wpk_bytes = (size_t)NPACK * 2;
    const size_t wgpk_bytes = (size_t)NPACKG * 2;
    short* a_b = (short*)ws;                      ws += ab_bytes;
    short* qbv = (short*)ws;                      ws += qb_bytes;
    short* kbv = (short*)ws;                      ws += kb_bytes;
    short* vbt = (short*)ws;                      ws += vbt_bytes;
    short* xpb = (short*)ws;                      ws += xpb_bytes;
    short* wpk = (short*)ws;                      ws += wpk_bytes;
    short* wgpk = (short*)ws;                     ws += wgpk_bytes;
    short* wxp = (short*)ws;

    dim3 blk(256);
    k_init<<<dim3(NINITB), blk, 0, stream>>>(W_xi, Wq, Wk, Wv, tau,
                                             Wi_x, Wi_a, Wg_x, Wg_a, Wo_x, Wo_a,
                                             wpk, wgpk, wxp, kbv, vbt, xpb);
    k_projM<<<dim3(21, 2, NB), blk, 0, stream>>>(x_in, wxp, xpb);
    k_qkvM<<<dim3(64, 4, 3), dim3(512), 0, stream>>>(xpb, wpk, qbv, kbv, vbt);
    k_attn<<<dim3(64, 11), dim3(512), 0, stream>>>(qbv, kbv, vbt, a_b);
    k_gatesM<<<dim3(64, 4), dim3(512), 0, stream>>>(xpb, a_b, wgpk,
                                                    b_i, g_i, b_g, g_g, b_o, g_o,
                                                    out);
}

// Round 18
// 82.036 us; speedup vs baseline: 1.2855x; 1.0161x over previous
//
#include <hip/hip_runtime.h>
#include <math.h>

typedef __attribute__((ext_vector_type(8))) short short8;
typedef __attribute__((ext_vector_type(4))) float f32x4;

#define NB   8
#define CIN  128
#define CC   256
#define GG   8
#define CGR  32
#define HH   36
#define WW   36
#define HWP  1296
#define DHH  34
#define DD   1156

#define PPW  38
#define PPN  1444

#define KB_D 1216
#define VBT_STRIDE 1216
#define VBT_NG     (32 * VBT_STRIDE)

#define AW   8
#define KS   40
#define VS   72
#define WS2  72

#define NPROJB (21 * 2 * NB)              // 336 proj blocks (chunk, oh, n)
#define NPACK  (3 * 8 * 9 * 32 * 32)      // 221184
#define NPACKG (8 * 3 * 10 * 32 * 32)     // 245760
#define ZPERNG (2432 + 2304 + 1920 + 1920)
#define NZERO  (64 * ZPERNG)              // 548864
#define NINIT  (NPACK + NPACKG + NZERO)   // 1015808
#define NINITB ((NINIT + 255) / 256)      // 3968

__device__ inline short f2bf(float f) {
    union { float f; unsigned u; } v; v.f = f;
    unsigned r = v.u + 0x7fffu + ((v.u >> 16) & 1u);
    return (short)(r >> 16);
}

__device__ inline float sigm(float z) { return 1.f / (1.f + __expf(-z)); }
__device__ inline float tanh_fast(float z) { return 2.f / (1.f + __expf(-2.f * z)) - 1.f; }

// ---------------- fused init: MFMA proj (blocks [0,336)) + packs + pad zeroing ----------------
// Proj stages W_xi straight from fp32 global into swizzled bf16 LDS (no wxp buffer).
__global__ __launch_bounds__(256) void k_initP(const float* __restrict__ x_in,
                                               const float* __restrict__ W_xi,
                                               const float* __restrict__ Wq,
                                               const float* __restrict__ Wk,
                                               const float* __restrict__ Wv,
                                               const float* __restrict__ tau,
                                               const float* __restrict__ Wi_x, const float* __restrict__ Wi_a,
                                               const float* __restrict__ Wg_x, const float* __restrict__ Wg_a,
                                               const float* __restrict__ Wo_x, const float* __restrict__ Wo_a,
                                               short* __restrict__ wpk,
                                               short* __restrict__ wgpk,
                                               short* __restrict__ kb,
                                               short* __restrict__ vbt,
                                               short* __restrict__ xpb) {
    __shared__ short b_lds[4 * 128 * 32];
    int bid = blockIdx.x;
    if (bid < NPROJB) {
        // ---- MFMA 1x1 projection (math verbatim round-16 k_projM) ----
        int chunk = bid % 21, oh = (bid / 21) & 1, n = bid / 42;
        const float* wb = W_xi + (size_t)oh * 128 * CIN;
        for (int e8 = threadIdx.x; e8 < 2048; e8 += 256) {
            short tmp[8];
            #pragma unroll
            for (int j = 0; j < 8; j++) {
                int e = e8 * 8 + j;
                int cpos = e & 31;
                int ocp  = (e >> 5) & 127;
                int sc   = (e >> 12) & 3;
                int ci = sc * 32 + (cpos ^ ((ocp & 3) << 3));
                tmp[j] = f2bf(wb[(size_t)ocp * CIN + ci]);
            }
            *(uint4*)(&b_lds[e8 * 8]) = *(uint4*)tmp;
        }
        __syncthreads();

        int tid = threadIdx.x;
        int wv = tid >> 6, ln = tid & 63, lo = ln & 15, hi = ln >> 4;
        int tile = chunk * 4 + wv;
        bool tv = (tile < 81);
        int swz = (hi * 8) ^ ((lo & 3) << 3);

        if (tv) {
            int px = tile * 16 + lo;
            const float* xb = x_in + (size_t)n * CIN * HWP + px;
            short8 af[4];
            #pragma unroll
            for (int sc = 0; sc < 4; sc++) {
                short tmp[8];
                #pragma unroll
                for (int j2 = 0; j2 < 8; j2++)
                    tmp[j2] = f2bf(xb[(size_t)(sc * 32 + hi * 8 + j2) * HWP]);
                af[sc] = *(short8*)tmp;
            }

            f32x4 acc[8];
            #pragma unroll
            for (int ot = 0; ot < 8; ot++) acc[ot] = (f32x4){0.f, 0.f, 0.f, 0.f};
            #pragma unroll
            for (int sc = 0; sc < 4; sc++) {
                #pragma unroll
                for (int ot = 0; ot < 8; ot++) {
                    short8 bf = *(const short8*)(&b_lds[sc * 4096 + (ot * 16 + lo) * 32 + swz]);
                    acc[ot] = __builtin_amdgcn_mfma_f32_16x16x32_bf16(af[sc], bf, acc[ot], 0, 0, 0);
                }
            }

            #pragma unroll
            for (int ot = 0; ot < 8; ot++) {
                int ocg = oh * 128 + ot * 16 + lo;
                int g = ocg >> 5, c = ocg & 31;
                short* xgw = xpb + (size_t)(n * GG + g) * PPN * 32 + c;
                #pragma unroll
                for (int r = 0; r < 4; r++) {
                    int p = tile * 16 + hi * 4 + r;
                    int y = p / 36, xx = p - y * 36;
                    xgw[(size_t)((y + 1) * PPW + xx + 1) * 32] = f2bf(acc[ot][r]);
                }
            }
        }
        return;
    }

    int idx = (bid - NPROJB) * 256 + threadIdx.x;
    if (idx < NPACK) {
        int cpos = idx & 31;
        int oc   = (idx >> 5) & 31;
        int tap  = (idx >> 10) % 9;
        int cg   = idx / 9216;
        int conv = cg >> 3, g = cg & 7;
        int ci = cpos ^ ((oc & 3) << 3);
        const float* W = (conv == 0) ? Wq : (conv == 1) ? Wk : Wv;
        float v = W[(size_t)(g * 32 + oc) * 576 + ci * 9 + tap];
        if (conv == 0) v *= tau[g] * 1.4426950408889634f;
        wpk[idx] = f2bf(v);
        return;
    }
    idx -= NPACK;
    if (idx < NPACKG) {
        int cpos = idx & 31;
        int oc   = (idx >> 5) & 31;
        int tap  = (idx >> 10) % 10;
        int gg_  = idx / 10240;
        int g    = gg_ / 3, gate = gg_ % 3;
        int ci = cpos ^ ((oc & 3) << 3);
        const float* Wx = (gate == 0) ? Wi_x : (gate == 1) ? Wg_x : Wo_x;
        const float* Wa = (gate == 0) ? Wi_a : (gate == 1) ? Wg_a : Wo_a;
        float v = (tap < 9) ? Wx[(size_t)(g * 32 + oc) * 576 + ci * 9 + tap]
                            : Wa[(g * 32 + oc) * 32 + ci];
        wgpk[idx] = f2bf(v);
        return;
    }
    idx -= NPACKG;
    if (idx >= NZERO) return;
    int ng = idx / ZPERNG;
    int r  = idx % ZPERNG;
    if (r < 2432) {
        int row = (r < 1216) ? 0 : 37;
        int off = (r < 1216) ? r : r - 1216;
        xpb[(size_t)ng * PPN * 32 + (size_t)row * 1216 + off] = 0;
    } else if (r < 4736) {
        int r2 = r - 2432;
        int row = 1 + r2 / 64;
        int rem = r2 % 64;
        int col = (rem < 32) ? 0 : 37;
        int ch = rem & 31;
        xpb[(size_t)ng * PPN * 32 + (size_t)(row * PPW + col) * 32 + ch] = 0;
    } else if (r < 6656) {
        int r3 = r - 4736;
        kb[(size_t)ng * KB_D * 32 + (size_t)DD * 32 + r3] = 0;
    } else {
        int r4 = r - 6656;
        int c = r4 / 60, d = r4 % 60;
        vbt[(size_t)ng * VBT_NG + (size_t)c * VBT_STRIDE + DD + d] = 0;
    }
}

// ---------------- MFMA grouped 3x3 conv q/k/v (verbatim round-17) ----------------
__global__ __launch_bounds__(512) void k_qkvM(const short* __restrict__ xpb,
                                              const short* __restrict__ wpk,
                                              short* __restrict__ qb,
                                              short* __restrict__ kb,
                                              short* __restrict__ vbt) {
    __shared__ short w_lds[9 * 32 * 32];
    int ng = blockIdx.x, chunk = blockIdx.y, conv = blockIdx.z;
    int n = ng >> 3, g = ng & 7;

    const short* wsrc = wpk + (size_t)(conv * 8 + g) * 9216;
    for (int idx = threadIdx.x; idx < 1152; idx += 512)
        *(uint4*)(&w_lds[idx * 8]) = *(const uint4*)(wsrc + idx * 8);
    __syncthreads();

    int tid = threadIdx.x;
    int wv = tid >> 6, ln = tid & 63, lo = ln & 15, hi = ln >> 4;
    const short* xg = xpb + (size_t)(n * GG + g) * PPN * 32;
    int swz = (hi * 8) ^ ((lo & 3) << 3);

    f32x4 acc[3][2];
    #pragma unroll
    for (int tt = 0; tt < 3; tt++)
        #pragma unroll
        for (int ot = 0; ot < 2; ot++) acc[tt][ot] = (f32x4){0.f, 0.f, 0.f, 0.f};

    int tbase = chunk * 24 + wv * 3;
    #pragma unroll
    for (int tt = 0; tt < 3; tt++) {
        int tile = tbase + tt;
        if (tile < 81) {
            int p = tile * 16 + lo;
            int y = p / 36, xx = p - y * 36;
            const short* ab = xg + ((size_t)((y + 1) * PPW + xx + 1) * 32 + hi * 8);
            #pragma unroll
            for (int tap = 0; tap < 9; tap++) {
                int toff = (tap / 3 - 1) * PPW + (tap % 3 - 1);
                short8 af = *(const short8*)(ab + toff * 32);
                short8 b0 = *(const short8*)(&w_lds[tap * 1024 + lo * 32 + swz]);
                short8 b1 = *(const short8*)(&w_lds[tap * 1024 + (16 + lo) * 32 + swz]);
                acc[tt][0] = __builtin_amdgcn_mfma_f32_16x16x32_bf16(af, b0, acc[tt][0], 0, 0, 0);
                acc[tt][1] = __builtin_amdgcn_mfma_f32_16x16x32_bf16(af, b1, acc[tt][1], 0, 0, 0);
            }
        }
    }

    size_t bofs = (size_t)n * GG + g;
    #pragma unroll
    for (int tt = 0; tt < 3; tt++) {
        int tile = tbase + tt;
        if (tile < 81) {
            #pragma unroll
            for (int r = 0; r < 4; r++) {
                int p = tile * 16 + hi * 4 + r;
                int y = p / 36, xx = p - y * 36;
                #pragma unroll
                for (int ot = 0; ot < 2; ot++) {
                    short val = f2bf(acc[tt][ot][r]);
                    int oc = ot * 16 + lo;
                    if (conv == 0) {
                        qb[bofs * ((size_t)HWP * 32) + (size_t)p * 32 + oc] = val;
                    } else if ((unsigned)(y - 1) < DHH && (unsigned)(xx - 1) < DHH) {
                        int d = (y - 1) * DHH + (xx - 1);
                        if (conv == 1) kb[bofs * ((size_t)KB_D * 32) + (size_t)d * 32 + oc] = val;
                        else           vbt[bofs * (size_t)VBT_NG + (size_t)oc * VBT_STRIDE + d] = val;
                    }
                }
            }
        }
    }
}

// ---------------- MFMA attention (verbatim round-9, known good) ----------------
__global__ __launch_bounds__(512) void k_attn(const short* __restrict__ qb,
                                              const short* __restrict__ kb,
                                              const short* __restrict__ vbt,
                                              short* __restrict__ a_b) {
    __shared__ short k_s[2][64 * KS];
    __shared__ short v_s[2][32 * VS];
    __shared__ short w_s[AW][16 * WS2];

    int ng = blockIdx.x, qc = blockIdx.y;
    int tid = threadIdx.x;
    int wv = tid >> 6, ln = tid & 63;
    int lo = ln & 15, hi = ln >> 4;
    const short* qg = qb + (size_t)ng * HWP * 32;
    const short* kg = kb + (size_t)ng * KB_D * 32;
    const short* vg = vbt + (size_t)ng * VBT_NG;
    short* ag = a_b + (size_t)ng * HWP * 32;

    int tile = qc * AW + wv;
    bool tv = (tile < 81);
    short8 qf = (short8){0,0,0,0,0,0,0,0};
    if (tv) qf = *(const short8*)(qg + (size_t)(tile * 16 + lo) * 32 + hi * 8);

    int kd = tid >> 2, kco = (tid & 3) << 3;
    int vc = (tid >> 3) & 31, vdo = (tid & 7) << 3;
    bool isK = (tid < 256);

    f32x4 oacc[2];
    oacc[0] = (f32x4){0.f, 0.f, 0.f, 0.f};
    oacc[1] = (f32x4){0.f, 0.f, 0.f, 0.f};
    float rs = 0.f;
    const f32x4 fz = {0.f, 0.f, 0.f, 0.f};

    {
        uint4 s0;
        if (isK) s0 = *(const uint4*)(kg + (size_t)kd * 32 + kco);
        else     s0 = *(const uint4*)(vg + (size_t)vc * VBT_STRIDE + vdo);
        if (isK) *(uint4*)(&k_s[0][kd * KS + kco]) = s0;
        else     *(uint4*)(&v_s[0][vc * VS + vdo]) = s0;
    }
    __syncthreads();

    for (int dt = 0; dt < 19; dt++) {
        int cur = dt & 1, nxt = cur ^ 1;
        uint4 nreg;
        if (dt < 18) {
            int d1 = (dt + 1) << 6;
            if (isK) nreg = *(const uint4*)(kg + (size_t)(d1 + kd) * 32 + kco);
            else     nreg = *(const uint4*)(vg + (size_t)vc * VBT_STRIDE + d1 + vdo);
        }

        if (tv) {
            #pragma unroll
            for (int sub = 0; sub < 4; sub++) {
                short8 kf = *(const short8*)(&k_s[cur][(sub * 16 + lo) * KS + hi * 8]);
                f32x4 s2 = __builtin_amdgcn_mfma_f32_16x16x32_bf16(kf, qf, fz, 0, 0, 0);
                float w0, w1, w2, w3;
                asm("v_exp_f32 %0, %1" : "=v"(w0) : "v"(s2[0]));
                asm("v_exp_f32 %0, %1" : "=v"(w1) : "v"(s2[1]));
                asm("v_exp_f32 %0, %1" : "=v"(w2) : "v"(s2[2]));
                asm("v_exp_f32 %0, %1" : "=v"(w3) : "v"(s2[3]));
                rs += (w0 + w1) + (w2 + w3);
                unsigned p01, p23;
                asm("v_cvt_pk_bf16_f32 %0, %1, %2" : "=v"(p01) : "v"(w0), "v"(w1));
                asm("v_cvt_pk_bf16_f32 %0, %1, %2" : "=v"(p23) : "v"(w2), "v"(w3));
                uint2 pk; pk.x = p01; pk.y = p23;
                *(uint2*)(&w_s[wv][lo * WS2 + sub * 16 + hi * 4]) = pk;
            }
            #pragma unroll
            for (int h = 0; h < 2; h++) {
                short8 af = *(const short8*)(&w_s[wv][lo * WS2 + h * 32 + hi * 8]);
                #pragma unroll
                for (int cs = 0; cs < 2; cs++) {
                    short8 vf = *(const short8*)(&v_s[cur][(cs * 16 + lo) * VS + h * 32 + hi * 8]);
                    oacc[cs] = __builtin_amdgcn_mfma_f32_16x16x32_bf16(af, vf, oacc[cs], 0, 0, 0);
                }
            }
        }

        if (dt < 18) {
            if (isK) *(uint4*)(&k_s[nxt][kd * KS + kco]) = nreg;
            else     *(uint4*)(&v_s[nxt][vc * VS + vdo]) = nreg;
        }
        __syncthreads();
    }

    float s = rs;
    s += __shfl_xor(s, 16);
    s += __shfl_xor(s, 32);
    float inv = 1.f / (s - 60.f);

    if (tv) {
        #pragma unroll
        for (int r = 0; r < 4; r++) {
            float iv = __shfl(inv, hi * 4 + r);
            int row = tile * 16 + hi * 4 + r;
            #pragma unroll
            for (int cs = 0; cs < 2; cs++)
                ag[(size_t)row * 32 + cs * 16 + lo] = f2bf(oacc[cs][r] * iv);
        }
    }
}

// ---------------- MFMA gates (verbatim round-17) ----------------
__global__ __launch_bounds__(512) void k_gatesM(const short* __restrict__ xpb,
                                                const short* __restrict__ a_b,
                                                const short* __restrict__ wgpk,
                                                const float* __restrict__ b_i, const float* __restrict__ g_i,
                                                const float* __restrict__ b_g, const float* __restrict__ g_g,
                                                const float* __restrict__ b_o, const float* __restrict__ g_o,
                                                float* __restrict__ out) {
    __shared__ short w_lds[3 * 10 * 32 * 32];
    int ng = blockIdx.x, chunk = blockIdx.y;
    int n = ng >> 3, g = ng & 7;

    const short* wsrc = wgpk + (size_t)g * 30720;
    for (int idx = threadIdx.x; idx < 3840; idx += 512)
        *(uint4*)(&w_lds[idx * 8]) = *(const uint4*)(wsrc + idx * 8);
    __syncthreads();

    int tid = threadIdx.x;
    int wv = tid >> 6, ln = tid & 63, lo = ln & 15, hi = ln >> 4;
    const short* xg = xpb + (size_t)(n * GG + g) * PPN * 32;
    const short* ab_a = a_b + (size_t)(n * GG + g) * HWP * 32;
    int swz = (hi * 8) ^ ((lo & 3) << 3);

    f32x4 acc[3][3][2];
    #pragma unroll
    for (int gt = 0; gt < 3; gt++)
        #pragma unroll
        for (int tt = 0; tt < 3; tt++)
            #pragma unroll
            for (int ot = 0; ot < 2; ot++) acc[gt][tt][ot] = (f32x4){0.f, 0.f, 0.f, 0.f};

    int tbase = chunk * 24 + wv * 3;
    bool tv[3];
    int pbase[3];
    #pragma unroll
    for (int tt = 0; tt < 3; tt++) {
        int tile = tbase + tt;
        tv[tt] = (tile < 81);
        int p = tile * 16 + lo;
        int y = p / 36, xx = p - y * 36;
        pbase[tt] = ((y + 1) * PPW + xx + 1) * 32 + hi * 8;
    }

    #pragma unroll
    for (int tap = 0; tap < 9; tap++) {
        int toff = (tap / 3 - 1) * PPW + (tap % 3 - 1);
        short8 af[3];
        #pragma unroll
        for (int tt = 0; tt < 3; tt++) {
            af[tt] = (short8){0,0,0,0,0,0,0,0};
            if (tv[tt]) af[tt] = *(const short8*)(xg + pbase[tt] + toff * 32);
        }
        #pragma unroll
        for (int gt = 0; gt < 3; gt++) {
            const short* wl = &w_lds[(gt * 10 + tap) * 1024];
            short8 b0 = *(const short8*)(&wl[lo * 32 + swz]);
            short8 b1 = *(const short8*)(&wl[(16 + lo) * 32 + swz]);
            #pragma unroll
            for (int tt = 0; tt < 3; tt++) {
                acc[gt][tt][0] = __builtin_amdgcn_mfma_f32_16x16x32_bf16(af[tt], b0, acc[gt][tt][0], 0, 0, 0);
                acc[gt][tt][1] = __builtin_amdgcn_mfma_f32_16x16x32_bf16(af[tt], b1, acc[gt][tt][1], 0, 0, 0);
            }
        }
    }
    {
        short8 af[3];
        #pragma unroll
        for (int tt = 0; tt < 3; tt++) {
            af[tt] = (short8){0,0,0,0,0,0,0,0};
            if (tv[tt]) af[tt] = *(const short8*)(ab_a + (size_t)((tbase + tt) * 16 + lo) * 32 + hi * 8);
        }
        #pragma unroll
        for (int gt = 0; gt < 3; gt++) {
            const short* wl = &w_lds[(gt * 10 + 9) * 1024];
            short8 b0 = *(const short8*)(&wl[lo * 32 + swz]);
            short8 b1 = *(const short8*)(&wl[(16 + lo) * 32 + swz]);
            #pragma unroll
            for (int tt = 0; tt < 3; tt++) {
                acc[gt][tt][0] = __builtin_amdgcn_mfma_f32_16x16x32_bf16(af[tt], b0, acc[gt][tt][0], 0, 0, 0);
                acc[gt][tt][1] = __builtin_amdgcn_mfma_f32_16x16x32_bf16(af[tt], b1, acc[gt][tt][1], 0, 0, 0);
            }
        }
    }

    int oc0 = g * 32 + lo, oc1 = oc0 + 16;
    float gi0 = g_i[oc0], gi1 = g_i[oc1], bi0 = b_i[oc0], bi1 = b_i[oc1];
    float gg0 = g_g[oc0], gg1 = g_g[oc1], bg0 = b_g[oc0], bg1 = b_g[oc1];
    float go0 = g_o[oc0], go1 = g_o[oc1], bo0 = b_o[oc0], bo1 = b_o[oc1];

    #pragma unroll
    for (int tt = 0; tt < 3; tt++) {
        if (tv[tt]) {
            int tile = tbase + tt;
            #pragma unroll
            for (int r = 0; r < 4; r++) {
                int p = tile * 16 + hi * 4 + r;
                #pragma unroll
                for (int ot = 0; ot < 2; ot++) {
                    float gi = ot ? gi1 : gi0, bi = ot ? bi1 : bi0;
                    float gg_ = ot ? gg1 : gg0, bg = ot ? bg1 : bg0;
                    float go = ot ? go1 : go0, bo = ot ? bo1 : bo0;
                    float iv = sigm(gi * acc[0][tt][ot][r] + bi);
                    float gv = tanh_fast(gg_ * acc[1][tt][ot][r] + bg);
                    float ov = sigm(go * acc[2][tt][ot][r] + bo);
                    int oc = g * 32 + ot * 16 + lo;
                    out[((size_t)n * CC + oc) * HWP + p] = ov * tanh_fast(iv * gv);
                }
            }
        }
    }
}

extern "C" void kernel_launch(void* const* d_in, const int* in_sizes, int n_in,
                              void* d_out, int out_size, void* d_ws, size_t ws_size,
                              hipStream_t stream) {
    const float* x_in = (const float*)d_in[0];
    const float* W_xi = (const float*)d_in[2];
    const float* Wq   = (const float*)d_in[3];
    const float* Wk   = (const float*)d_in[4];
    const float* Wv   = (const float*)d_in[5];
    const float* Wi_a = (const float*)d_in[6];
    const float* Wi_x = (const float*)d_in[7];
    const float* b_i  = (const float*)d_in[8];
    const float* g_i  = (const float*)d_in[9];
    const float* Wg_a = (const float*)d_in[14];
    const float* Wg_x = (const float*)d_in[15];
    const float* b_g  = (const float*)d_in[16];
    const float* g_g  = (const float*)d_in[17];
    const float* Wo_a = (const float*)d_in[18];
    const float* Wo_x = (const float*)d_in[19];
    const float* b_o  = (const float*)d_in[20];
    const float* g_o  = (const float*)d_in[21];
    const float* tau  = (const float*)d_in[22];
    float* out = (float*)d_out;

    char* ws = (char*)d_ws;
    const size_t ab_bytes  = (size_t)NB * GG * HWP * 32 * 2;
    const size_t qb_bytes  = (size_t)NB * GG * HWP * 32 * 2;
    const size_t kb_bytes  = (size_t)NB * GG * KB_D * 32 * 2;
    const size_t vbt_bytes = (size_t)NB * GG * VBT_NG * 2;
    const size_t xpb_bytes = (size_t)NB * GG * PPN * 32 * 2;
    const size_t wpk_bytes = (size_t)NPACK * 2;
    short* a_b = (short*)ws;                      ws += ab_bytes;
    short* qbv = (short*)ws;                      ws += qb_bytes;
    short* kbv = (short*)ws;                      ws += kb_bytes;
    short* vbt = (short*)ws;                      ws += vbt_bytes;
    short* xpb = (short*)ws;                      ws += xpb_bytes;
    short* wpk = (short*)ws;                      ws += wpk_bytes;
    short* wgpk = (short*)ws;

    dim3 blk(256);
    k_initP<<<dim3(NPROJB + NINITB), blk, 0, stream>>>(x_in, W_xi, Wq, Wk, Wv, tau,
                                                       Wi_x, Wi_a, Wg_x, Wg_a, Wo_x, Wo_a,
                                                       wpk, wgpk, kbv, vbt, xpb);
    k_qkvM<<<dim3(64, 4, 3), dim3(512), 0, stream>>>(xpb, wpk, qbv, kbv, vbt);
    k_attn<<<dim3(64, 11), dim3(512), 0, stream>>>(qbv, kbv, vbt, a_b);
    k_gatesM<<<dim3(64, 4), dim3(512), 0, stream>>>(xpb, a_b, wgpk,
                                                    b_i, g_i, b_g, g_g, b_o, g_o,
                                                    out);
}

// Round 20
// 81.093 us; speedup vs baseline: 1.3004x; 1.0116x over previous
//
#include <hip/hip_runtime.h>
#include <math.h>

typedef __attribute__((ext_vector_type(8))) short short8;
typedef __attribute__((ext_vector_type(4))) float f32x4;

#define NB   8
#define CIN  128
#define CC   256
#define GG   8
#define CGR  32
#define HH   36
#define WW   36
#define HWP  1296
#define DHH  34
#define DD   1156

#define PPW  38
#define PPN  1444

#define KB_D 1216
#define VBT_STRIDE 1216
#define VBT_NG     (32 * VBT_STRIDE)

#define AW   8
#define KS   40
#define VS   72
#define WS2  72

#define NPROJB (21 * 2 * NB)              // 336 proj blocks
#define NPACK  (3 * 8 * 9 * 32 * 32)      // 221184
#define NPACKG (8 * 3 * 10 * 32 * 32)     // 245760
#define ZPERNG (2432 + 2304 + 1920 + 1920)
#define NZERO  (64 * ZPERNG)              // 548864
#define NINIT  (NPACK + NPACKG + NZERO)   // 1015808
#define NINITB ((NINIT + 255) / 256)      // 3968

__device__ inline short f2bf(float f) {
    union { float f; unsigned u; } v; v.f = f;
    unsigned r = v.u + 0x7fffu + ((v.u >> 16) & 1u);
    return (short)(r >> 16);
}

__device__ inline float sigm(float z) { return 1.f / (1.f + __expf(-z)); }
__device__ inline float tanh_fast(float z) { return 2.f / (1.f + __expf(-2.f * z)) - 1.f; }

// ---------------- fused init: MFMA proj + packs + pad zeroing (verbatim round-18) ----------------
__global__ __launch_bounds__(256) void k_initP(const float* __restrict__ x_in,
                                               const float* __restrict__ W_xi,
                                               const float* __restrict__ Wq,
                                               const float* __restrict__ Wk,
                                               const float* __restrict__ Wv,
                                               const float* __restrict__ tau,
                                               const float* __restrict__ Wi_x, const float* __restrict__ Wi_a,
                                               const float* __restrict__ Wg_x, const float* __restrict__ Wg_a,
                                               const float* __restrict__ Wo_x, const float* __restrict__ Wo_a,
                                               short* __restrict__ wpk,
                                               short* __restrict__ wgpk,
                                               short* __restrict__ kb,
                                               short* __restrict__ vbt,
                                               short* __restrict__ xpb) {
    __shared__ short b_lds[4 * 128 * 32];
    int bid = blockIdx.x;
    if (bid < NPROJB) {
        int chunk = bid % 21, oh = (bid / 21) & 1, n = bid / 42;
        const float* wb = W_xi + (size_t)oh * 128 * CIN;
        for (int e8 = threadIdx.x; e8 < 2048; e8 += 256) {
            short tmp[8];
            #pragma unroll
            for (int j = 0; j < 8; j++) {
                int e = e8 * 8 + j;
                int cpos = e & 31;
                int ocp  = (e >> 5) & 127;
                int sc   = (e >> 12) & 3;
                int ci = sc * 32 + (cpos ^ ((ocp & 3) << 3));
                tmp[j] = f2bf(wb[(size_t)ocp * CIN + ci]);
            }
            *(uint4*)(&b_lds[e8 * 8]) = *(uint4*)tmp;
        }
        __syncthreads();

        int tid = threadIdx.x;
        int wv = tid >> 6, ln = tid & 63, lo = ln & 15, hi = ln >> 4;
        int tile = chunk * 4 + wv;
        bool tv = (tile < 81);
        int swz = (hi * 8) ^ ((lo & 3) << 3);

        if (tv) {
            int px = tile * 16 + lo;
            const float* xb = x_in + (size_t)n * CIN * HWP + px;
            short8 af[4];
            #pragma unroll
            for (int sc = 0; sc < 4; sc++) {
                short tmp[8];
                #pragma unroll
                for (int j2 = 0; j2 < 8; j2++)
                    tmp[j2] = f2bf(xb[(size_t)(sc * 32 + hi * 8 + j2) * HWP]);
                af[sc] = *(short8*)tmp;
            }

            f32x4 acc[8];
            #pragma unroll
            for (int ot = 0; ot < 8; ot++) acc[ot] = (f32x4){0.f, 0.f, 0.f, 0.f};
            #pragma unroll
            for (int sc = 0; sc < 4; sc++) {
                #pragma unroll
                for (int ot = 0; ot < 8; ot++) {
                    short8 bf = *(const short8*)(&b_lds[sc * 4096 + (ot * 16 + lo) * 32 + swz]);
                    acc[ot] = __builtin_amdgcn_mfma_f32_16x16x32_bf16(af[sc], bf, acc[ot], 0, 0, 0);
                }
            }

            #pragma unroll
            for (int ot = 0; ot < 8; ot++) {
                int ocg = oh * 128 + ot * 16 + lo;
                int g = ocg >> 5, c = ocg & 31;
                short* xgw = xpb + (size_t)(n * GG + g) * PPN * 32 + c;
                #pragma unroll
                for (int r = 0; r < 4; r++) {
                    int p = tile * 16 + hi * 4 + r;
                    int y = p / 36, xx = p - y * 36;
                    xgw[(size_t)((y + 1) * PPW + xx + 1) * 32] = f2bf(acc[ot][r]);
                }
            }
        }
        return;
    }

    int idx = (bid - NPROJB) * 256 + threadIdx.x;
    if (idx < NPACK) {
        int cpos = idx & 31;
        int oc   = (idx >> 5) & 31;
        int tap  = (idx >> 10) % 9;
        int cg   = idx / 9216;
        int conv = cg >> 3, g = cg & 7;
        int ci = cpos ^ ((oc & 3) << 3);
        const float* W = (conv == 0) ? Wq : (conv == 1) ? Wk : Wv;
        float v = W[(size_t)(g * 32 + oc) * 576 + ci * 9 + tap];
        if (conv == 0) v *= tau[g] * 1.4426950408889634f;
        wpk[idx] = f2bf(v);
        return;
    }
    idx -= NPACK;
    if (idx < NPACKG) {
        int cpos = idx & 31;
        int oc   = (idx >> 5) & 31;
        int tap  = (idx >> 10) % 10;
        int gg_  = idx / 10240;
        int g    = gg_ / 3, gate = gg_ % 3;
        int ci = cpos ^ ((oc & 3) << 3);
        const float* Wx = (gate == 0) ? Wi_x : (gate == 1) ? Wg_x : Wo_x;
        const float* Wa = (gate == 0) ? Wi_a : (gate == 1) ? Wg_a : Wo_a;
        float v = (tap < 9) ? Wx[(size_t)(g * 32 + oc) * 576 + ci * 9 + tap]
                            : Wa[(g * 32 + oc) * 32 + ci];
        wgpk[idx] = f2bf(v);
        return;
    }
    idx -= NPACKG;
    if (idx >= NZERO) return;
    int ng = idx / ZPERNG;
    int r  = idx % ZPERNG;
    if (r < 2432) {
        int row = (r < 1216) ? 0 : 37;
        int off = (r < 1216) ? r : r - 1216;
        xpb[(size_t)ng * PPN * 32 + (size_t)row * 1216 + off] = 0;
    } else if (r < 4736) {
        int r2 = r - 2432;
        int row = 1 + r2 / 64;
        int rem = r2 % 64;
        int col = (rem < 32) ? 0 : 37;
        int ch = rem & 31;
        xpb[(size_t)ng * PPN * 32 + (size_t)(row * PPW + col) * 32 + ch] = 0;
    } else if (r < 6656) {
        int r3 = r - 4736;
        kb[(size_t)ng * KB_D * 32 + (size_t)DD * 32 + r3] = 0;
    } else {
        int r4 = r - 6656;
        int c = r4 / 60, d = r4 % 60;
        vbt[(size_t)ng * VBT_NG + (size_t)c * VBT_STRIDE + DD + d] = 0;
    }
}

// ---------------- MFMA grouped 3x3 conv q/k/v (verbatim round-17) ----------------
__global__ __launch_bounds__(512) void k_qkvM(const short* __restrict__ xpb,
                                              const short* __restrict__ wpk,
                                              short* __restrict__ qb,
                                              short* __restrict__ kb,
                                              short* __restrict__ vbt) {
    __shared__ short w_lds[9 * 32 * 32];
    int ng = blockIdx.x, chunk = blockIdx.y, conv = blockIdx.z;
    int n = ng >> 3, g = ng & 7;

    const short* wsrc = wpk + (size_t)(conv * 8 + g) * 9216;
    for (int idx = threadIdx.x; idx < 1152; idx += 512)
        *(uint4*)(&w_lds[idx * 8]) = *(const uint4*)(wsrc + idx * 8);
    __syncthreads();

    int tid = threadIdx.x;
    int wv = tid >> 6, ln = tid & 63, lo = ln & 15, hi = ln >> 4;
    const short* xg = xpb + (size_t)(n * GG + g) * PPN * 32;
    int swz = (hi * 8) ^ ((lo & 3) << 3);

    f32x4 acc[3][2];
    #pragma unroll
    for (int tt = 0; tt < 3; tt++)
        #pragma unroll
        for (int ot = 0; ot < 2; ot++) acc[tt][ot] = (f32x4){0.f, 0.f, 0.f, 0.f};

    int tbase = chunk * 24 + wv * 3;
    #pragma unroll
    for (int tt = 0; tt < 3; tt++) {
        int tile = tbase + tt;
        if (tile < 81) {
            int p = tile * 16 + lo;
            int y = p / 36, xx = p - y * 36;
            const short* ab = xg + ((size_t)((y + 1) * PPW + xx + 1) * 32 + hi * 8);
            #pragma unroll
            for (int tap = 0; tap < 9; tap++) {
                int toff = (tap / 3 - 1) * PPW + (tap % 3 - 1);
                short8 af = *(const short8*)(ab + toff * 32);
                short8 b0 = *(const short8*)(&w_lds[tap * 1024 + lo * 32 + swz]);
                short8 b1 = *(const short8*)(&w_lds[tap * 1024 + (16 + lo) * 32 + swz]);
                acc[tt][0] = __builtin_amdgcn_mfma_f32_16x16x32_bf16(af, b0, acc[tt][0], 0, 0, 0);
                acc[tt][1] = __builtin_amdgcn_mfma_f32_16x16x32_bf16(af, b1, acc[tt][1], 0, 0, 0);
            }
        }
    }

    size_t bofs = (size_t)n * GG + g;
    #pragma unroll
    for (int tt = 0; tt < 3; tt++) {
        int tile = tbase + tt;
        if (tile < 81) {
            #pragma unroll
            for (int r = 0; r < 4; r++) {
                int p = tile * 16 + hi * 4 + r;
                int y = p / 36, xx = p - y * 36;
                #pragma unroll
                for (int ot = 0; ot < 2; ot++) {
                    short val = f2bf(acc[tt][ot][r]);
                    int oc = ot * 16 + lo;
                    if (conv == 0) {
                        qb[bofs * ((size_t)HWP * 32) + (size_t)p * 32 + oc] = val;
                    } else if ((unsigned)(y - 1) < DHH && (unsigned)(xx - 1) < DHH) {
                        int d = (y - 1) * DHH + (xx - 1);
                        if (conv == 1) kb[bofs * ((size_t)KB_D * 32) + (size_t)d * 32 + oc] = val;
                        else           vbt[bofs * (size_t)VBT_NG + (size_t)oc * VBT_STRIDE + d] = val;
                    }
                }
            }
        }
    }
}

// ---------------- MFMA attention (round-9 structure + T5 setprio around compute) ----------------
__global__ __launch_bounds__(512) void k_attn(const short* __restrict__ qb,
                                              const short* __restrict__ kb,
                                              const short* __restrict__ vbt,
                                              short* __restrict__ a_b) {
    __shared__ short k_s[2][64 * KS];
    __shared__ short v_s[2][32 * VS];
    __shared__ short w_s[AW][16 * WS2];

    int ng = blockIdx.x, qc = blockIdx.y;
    int tid = threadIdx.x;
    int wv = tid >> 6, ln = tid & 63;
    int lo = ln & 15, hi = ln >> 4;
    const short* qg = qb + (size_t)ng * HWP * 32;
    const short* kg = kb + (size_t)ng * KB_D * 32;
    const short* vg = vbt + (size_t)ng * VBT_NG;
    short* ag = a_b + (size_t)ng * HWP * 32;

    int tile = qc * AW + wv;
    bool tv = (tile < 81);
    short8 qf = (short8){0,0,0,0,0,0,0,0};
    if (tv) qf = *(const short8*)(qg + (size_t)(tile * 16 + lo) * 32 + hi * 8);

    int kd = tid >> 2, kco = (tid & 3) << 3;
    int vc = (tid >> 3) & 31, vdo = (tid & 7) << 3;
    bool isK = (tid < 256);

    f32x4 oacc[2];
    oacc[0] = (f32x4){0.f, 0.f, 0.f, 0.f};
    oacc[1] = (f32x4){0.f, 0.f, 0.f, 0.f};
    float rs = 0.f;
    const f32x4 fz = {0.f, 0.f, 0.f, 0.f};

    {
        uint4 s0;
        if (isK) s0 = *(const uint4*)(kg + (size_t)kd * 32 + kco);
        else     s0 = *(const uint4*)(vg + (size_t)vc * VBT_STRIDE + vdo);
        if (isK) *(uint4*)(&k_s[0][kd * KS + kco]) = s0;
        else     *(uint4*)(&v_s[0][vc * VS + vdo]) = s0;
    }
    __syncthreads();

    for (int dt = 0; dt < 19; dt++) {
        int cur = dt & 1, nxt = cur ^ 1;
        uint4 nreg;
        if (dt < 18) {
            int d1 = (dt + 1) << 6;
            if (isK) nreg = *(const uint4*)(kg + (size_t)(d1 + kd) * 32 + kco);
            else     nreg = *(const uint4*)(vg + (size_t)vc * VBT_STRIDE + d1 + vdo);
        }

        if (tv) {
            __builtin_amdgcn_s_setprio(1);
            #pragma unroll
            for (int sub = 0; sub < 4; sub++) {
                short8 kf = *(const short8*)(&k_s[cur][(sub * 16 + lo) * KS + hi * 8]);
                f32x4 s2 = __builtin_amdgcn_mfma_f32_16x16x32_bf16(kf, qf, fz, 0, 0, 0);
                float w0, w1, w2, w3;
                asm("v_exp_f32 %0, %1" : "=v"(w0) : "v"(s2[0]));
                asm("v_exp_f32 %0, %1" : "=v"(w1) : "v"(s2[1]));
                asm("v_exp_f32 %0, %1" : "=v"(w2) : "v"(s2[2]));
                asm("v_exp_f32 %0, %1" : "=v"(w3) : "v"(s2[3]));
                rs += (w0 + w1) + (w2 + w3);
                unsigned p01, p23;
                asm("v_cvt_pk_bf16_f32 %0, %1, %2" : "=v"(p01) : "v"(w0), "v"(w1));
                asm("v_cvt_pk_bf16_f32 %0, %1, %2" : "=v"(p23) : "v"(w2), "v"(w3));
                uint2 pk; pk.x = p01; pk.y = p23;
                *(uint2*)(&w_s[wv][lo * WS2 + sub * 16 + hi * 4]) = pk;
            }
            #pragma unroll
            for (int h = 0; h < 2; h++) {
                short8 af = *(const short8*)(&w_s[wv][lo * WS2 + h * 32 + hi * 8]);
                #pragma unroll
                for (int cs = 0; cs < 2; cs++) {
                    short8 vf = *(const short8*)(&v_s[cur][(cs * 16 + lo) * VS + h * 32 + hi * 8]);
                    oacc[cs] = __builtin_amdgcn_mfma_f32_16x16x32_bf16(af, vf, oacc[cs], 0, 0, 0);
                }
            }
            __builtin_amdgcn_s_setprio(0);
        }

        if (dt < 18) {
            if (isK) *(uint4*)(&k_s[nxt][kd * KS + kco]) = nreg;
            else     *(uint4*)(&v_s[nxt][vc * VS + vdo]) = nreg;
        }
        __syncthreads();
    }

    float s = rs;
    s += __shfl_xor(s, 16);
    s += __shfl_xor(s, 32);
    float inv = 1.f / (s - 60.f);

    if (tv) {
        #pragma unroll
        for (int r = 0; r < 4; r++) {
            float iv = __shfl(inv, hi * 4 + r);
            int row = tile * 16 + hi * 4 + r;
            #pragma unroll
            for (int cs = 0; cs < 2; cs++)
                ag[(size_t)row * 32 + cs * 16 + lo] = f2bf(oacc[cs][r] * iv);
        }
    }
}

// ---------------- MFMA gates (verbatim round-17) ----------------
__global__ __launch_bounds__(512) void k_gatesM(const short* __restrict__ xpb,
                                                const short* __restrict__ a_b,
                                                const short* __restrict__ wgpk,
                                                const float* __restrict__ b_i, const float* __restrict__ g_i,
                                                const float* __restrict__ b_g, const float* __restrict__ g_g,
                                                const float* __restrict__ b_o, const float* __restrict__ g_o,
                                                float* __restrict__ out) {
    __shared__ short w_lds[3 * 10 * 32 * 32];
    int ng = blockIdx.x, chunk = blockIdx.y;
    int n = ng >> 3, g = ng & 7;

    const short* wsrc = wgpk + (size_t)g * 30720;
    for (int idx = threadIdx.x; idx < 3840; idx += 512)
        *(uint4*)(&w_lds[idx * 8]) = *(const uint4*)(wsrc + idx * 8);
    __syncthreads();

    int tid = threadIdx.x;
    int wv = tid >> 6, ln = tid & 63, lo = ln & 15, hi = ln >> 4;
    const short* xg = xpb + (size_t)(n * GG + g) * PPN * 32;
    const short* ab_a = a_b + (size_t)(n * GG + g) * HWP * 32;
    int swz = (hi * 8) ^ ((lo & 3) << 3);

    f32x4 acc[3][3][2];
    #pragma unroll
    for (int gt = 0; gt < 3; gt++)
        #pragma unroll
        for (int tt = 0; tt < 3; tt++)
            #pragma unroll
            for (int ot = 0; ot < 2; ot++) acc[gt][tt][ot] = (f32x4){0.f, 0.f, 0.f, 0.f};

    int tbase = chunk * 24 + wv * 3;
    bool tv[3];
    int pbase[3];
    #pragma unroll
    for (int tt = 0; tt < 3; tt++) {
        int tile = tbase + tt;
        tv[tt] = (tile < 81);
        int p = tile * 16 + lo;
        int y = p / 36, xx = p - y * 36;
        pbase[tt] = ((y + 1) * PPW + xx + 1) * 32 + hi * 8;
    }

    #pragma unroll
    for (int tap = 0; tap < 9; tap++) {
        int toff = (tap / 3 - 1) * PPW + (tap % 3 - 1);
        short8 af[3];
        #pragma unroll
        for (int tt = 0; tt < 3; tt++) {
            af[tt] = (short8){0,0,0,0,0,0,0,0};
            if (tv[tt]) af[tt] = *(const short8*)(xg + pbase[tt] + toff * 32);
        }
        #pragma unroll
        for (int gt = 0; gt < 3; gt++) {
            const short* wl = &w_lds[(gt * 10 + tap) * 1024];
            short8 b0 = *(const short8*)(&wl[lo * 32 + swz]);
            short8 b1 = *(const short8*)(&wl[(16 + lo) * 32 + swz]);
            #pragma unroll
            for (int tt = 0; tt < 3; tt++) {
                acc[gt][tt][0] = __builtin_amdgcn_mfma_f32_16x16x32_bf16(af[tt], b0, acc[gt][tt][0], 0, 0, 0);
                acc[gt][tt][1] = __builtin_amdgcn_mfma_f32_16x16x32_bf16(af[tt], b1, acc[gt][tt][1], 0, 0, 0);
            }
        }
    }
    {
        short8 af[3];
        #pragma unroll
        for (int tt = 0; tt < 3; tt++) {
            af[tt] = (short8){0,0,0,0,0,0,0,0};
            if (tv[tt]) af[tt] = *(const short8*)(ab_a + (size_t)((tbase + tt) * 16 + lo) * 32 + hi * 8);
        }
        #pragma unroll
        for (int gt = 0; gt < 3; gt++) {
            const short* wl = &w_lds[(gt * 10 + 9) * 1024];
            short8 b0 = *(const short8*)(&wl[lo * 32 + swz]);
            short8 b1 = *(const short8*)(&wl[(16 + lo) * 32 + swz]);
            #pragma unroll
            for (int tt = 0; tt < 3; tt++) {
                acc[gt][tt][0] = __builtin_amdgcn_mfma_f32_16x16x32_bf16(af[tt], b0, acc[gt][tt][0], 0, 0, 0);
                acc[gt][tt][1] = __builtin_amdgcn_mfma_f32_16x16x32_bf16(af[tt], b1, acc[gt][tt][1], 0, 0, 0);
            }
        }
    }

    int oc0 = g * 32 + lo, oc1 = oc0 + 16;
    float gi0 = g_i[oc0], gi1 = g_i[oc1], bi0 = b_i[oc0], bi1 = b_i[oc1];
    float gg0 = g_g[oc0], gg1 = g_g[oc1], bg0 = b_g[oc0], bg1 = b_g[oc1];
    float go0 = g_o[oc0], go1 = g_o[oc1], bo0 = b_o[oc0], bo1 = b_o[oc1];

    #pragma unroll
    for (int tt = 0; tt < 3; tt++) {
        if (tv[tt]) {
            int tile = tbase + tt;
            #pragma unroll
            for (int r = 0; r < 4; r++) {
                int p = tile * 16 + hi * 4 + r;
                #pragma unroll
                for (int ot = 0; ot < 2; ot++) {
                    float gi = ot ? gi1 : gi0, bi = ot ? bi1 : bi0;
                    float gg_ = ot ? gg1 : gg0, bg = ot ? bg1 : bg0;
                    float go = ot ? go1 : go0, bo = ot ? bo1 : bo0;
                    float iv = sigm(gi * acc[0][tt][ot][r] + bi);
                    float gv = tanh_fast(gg_ * acc[1][tt][ot][r] + bg);
                    float ov = sigm(go * acc[2][tt][ot][r] + bo);
                    int oc = g * 32 + ot * 16 + lo;
                    out[((size_t)n * CC + oc) * HWP + p] = ov * tanh_fast(iv * gv);
                }
            }
        }
    }
}

extern "C" void kernel_launch(void* const* d_in, const int* in_sizes, int n_in,
                              void* d_out, int out_size, void* d_ws, size_t ws_size,
                              hipStream_t stream) {
    const float* x_in = (const float*)d_in[0];
    const float* W_xi = (const float*)d_in[2];
    const float* Wq   = (const float*)d_in[3];
    const float* Wk   = (const float*)d_in[4];
    const float* Wv   = (const float*)d_in[5];
    const float* Wi_a = (const float*)d_in[6];
    const float* Wi_x = (const float*)d_in[7];
    const float* b_i  = (const float*)d_in[8];
    const float* g_i  = (const float*)d_in[9];
    const float* Wg_a = (const float*)d_in[14];
    const float* Wg_x = (const float*)d_in[15];
    const float* b_g  = (const float*)d_in[16];
    const float* g_g  = (const float*)d_in[17];
    const float* Wo_a = (const float*)d_in[18];
    const float* Wo_x = (const float*)d_in[19];
    const float* b_o  = (const float*)d_in[20];
    const float* g_o  = (const float*)d_in[21];
    const float* tau  = (const float*)d_in[22];
    float* out = (float*)d_out;

    char* ws = (char*)d_ws;
    const size_t ab_bytes  = (size_t)NB * GG * HWP * 32 * 2;
    const size_t qb_bytes  = (size_t)NB * GG * HWP * 32 * 2;
    const size_t kb_bytes  = (size_t)NB * GG * KB_D * 32 * 2;
    const size_t vbt_bytes = (size_t)NB * GG * VBT_NG * 2;
    const size_t xpb_bytes = (size_t)NB * GG * PPN * 32 * 2;
    const size_t wpk_bytes = (size_t)NPACK * 2;
    short* a_b = (short*)ws;                      ws += ab_bytes;
    short* qbv = (short*)ws;                      ws += qb_bytes;
    short* kbv = (short*)ws;                      ws += kb_bytes;
    short* vbt = (short*)ws;                      ws += vbt_bytes;
    short* xpb = (short*)ws;                      ws += xpb_bytes;
    short* wpk = (short*)ws;                      ws += wpk_bytes;
    short* wgpk = (short*)ws;

    dim3 blk(256);
    k_initP<<<dim3(NPROJB + NINITB), blk, 0, stream>>>(x_in, W_xi, Wq, Wk, Wv, tau,
                                                       Wi_x, Wi_a, Wg_x, Wg_a, Wo_x, Wo_a,
                                                       wpk, wgpk, kbv, vbt, xpb);
    k_qkvM<<<dim3(64, 4, 3), dim3(512), 0, stream>>>(xpb, wpk, qbv, kbv, vbt);
    k_attn<<<dim3(64, 11), dim3(512), 0, stream>>>(qbv, kbv, vbt, a_b);
    k_gatesM<<<dim3(64, 4), dim3(512), 0, stream>>>(xpb, a_b, wgpk,
                                                    b_i, g_i, b_g, g_g, b_o, g_o,
                                                    out);
}